// Round 2
// baseline (3742.471 us; speedup 1.0000x reference)
//
#include <hip/hip_runtime.h>
#include <hip/hip_bf16.h>

#define N_NODES   50000
#define N_EDGES   800000
#define IN_DIM    64
#define HID       128
#define NUM_GRAPHS 256

typedef __bf16 bf16x8 __attribute__((ext_vector_type(8)));
typedef unsigned short u16x8 __attribute__((ext_vector_type(8)));
typedef float f32x4 __attribute__((ext_vector_type(4)));

__device__ __forceinline__ float b2f(unsigned short u) {
    return __uint_as_float(((unsigned int)u) << 16);
}
__device__ __forceinline__ unsigned short f2b(float f) {
    unsigned int x = __float_as_uint(f);
    x = (x + 0x7fffu + ((x >> 16) & 1u)) >> 16;   // RNE
    return (unsigned short)x;
}

// ---- dtype probe: even u16s of bf16 normals have sane exponents; of fp32 they are mantissa bits ----
__global__ void detect_kernel(const unsigned short* __restrict__ x, int* __restrict__ flag) {
    __shared__ int cnt;
    if (threadIdx.x == 0) cnt = 0;
    __syncthreads();
    int c = 0;
    for (int j = 0; j < 16; j++) {
        unsigned short u = x[2 * (threadIdx.x * 16 + j)];
        int e = (u >> 7) & 0xff;
        if (e <= 100 || e >= 140) c++;
    }
    atomicAdd(&cnt, c);
    __syncthreads();
    if (threadIdx.x == 0) *flag = (cnt > 1024) ? 1 : 0;   // 1 = fp32 inputs, 0 = bf16
}

__global__ void diag_kernel(unsigned short* out, unsigned short pat) {
    out[threadIdx.x] = pat;
}

__global__ void cvt_x_kernel(const void* __restrict__ x, float* __restrict__ h, int n,
                             const int* __restrict__ flagp) {
    int t = blockIdx.x * 256 + threadIdx.x;
    if (t >= n) return;
    int flag = *flagp;
    h[t] = flag ? ((const float*)x)[t] : b2f(((const unsigned short*)x)[t]);
}

// agg[dst][:] += h[src][:], float4 per thread; logc = log2(dim/4)
__global__ void scatter_kernel(const float* __restrict__ h, const int* __restrict__ src,
                               const int* __restrict__ dst, float* __restrict__ agg, int logc) {
    int t = blockIdx.x * 256 + threadIdx.x;
    int e = t >> logc;
    if (e >= N_EDGES) return;
    int f4 = t & ((1 << logc) - 1);
    int s = src[e], d = dst[e];
    float4 v = *(const float4*)(h + ((size_t)s << (logc + 2)) + f4 * 4);
    float* ap = agg + ((size_t)d << (logc + 2)) + f4 * 4;
    atomicAdd(ap + 0, v.x);
    atomicAdd(ap + 1, v.y);
    atomicAdd(ap + 2, v.z);
    atomicAdd(ap + 3, v.w);
}

// Wf[((t*KC + c)*64 + lane)*8 + j] = W[c*32 + (lane>>4)*8 + j][t*16 + (lane&15)]
__global__ void reorder_w_kernel(const void* __restrict__ W, unsigned short* __restrict__ Wf,
                                 int K, int KC, const int* __restrict__ flagp) {
    int idx = blockIdx.x * 256 + threadIdx.x;
    if (idx >= K * 128) return;
    int flag = *flagp;
    int j  = idx & 7;
    int l  = (idx >> 3) & 63;
    int tc = idx >> 9;
    int c  = tc % KC;
    int t  = tc / KC;
    int k  = c * 32 + (l >> 4) * 8 + j;
    int n  = t * 16 + (l & 15);
    Wf[idx] = flag ? f2b(((const float*)W)[k * 128 + n])
                   : ((const unsigned short*)W)[k * 128 + n];
}

// Out[M,128] = relu( (Hm (+ Ag if FUSE)) [M,K] @ W[K,128] + bias ), A fed as bf16 hi+lo split
template <int K, bool FUSE>
__global__ __launch_bounds__(256) void gemm_kernel(
    const float* __restrict__ Hm, const float* __restrict__ Ag,
    const unsigned short* __restrict__ Wf, const void* __restrict__ bias,
    float* __restrict__ Out, int M, const int* __restrict__ flagp) {
    constexpr int KC = K / 32;
    int flag = *flagp;
    int wave = threadIdx.x >> 6;
    int lane = threadIdx.x & 63;
    int m_ = lane & 15;
    int q  = lane >> 4;
    int rowbase = blockIdx.x * 64 + wave * 16;
    int row  = rowbase + m_;
    int rowc = row < M ? row : (M - 1);

    const float* hrow = Hm + (size_t)rowc * K + q * 8;
    const float* arow = FUSE ? (Ag + (size_t)rowc * K + q * 8) : nullptr;
    const unsigned short* wfl = Wf + lane * 8;

    f32x4 acc[8];
#pragma unroll
    for (int t = 0; t < 8; t++) acc[t] = (f32x4)(0.0f);

#pragma unroll
    for (int c = 0; c < KC; c++) {
        float4 h0 = *(const float4*)(hrow + c * 32);
        float4 h1 = *(const float4*)(hrow + c * 32 + 4);
        float vf[8] = {h0.x, h0.y, h0.z, h0.w, h1.x, h1.y, h1.z, h1.w};
        if constexpr (FUSE) {
            float4 a0 = *(const float4*)(arow + c * 32);
            float4 a1 = *(const float4*)(arow + c * 32 + 4);
            vf[0] += a0.x; vf[1] += a0.y; vf[2] += a0.z; vf[3] += a0.w;
            vf[4] += a1.x; vf[5] += a1.y; vf[6] += a1.z; vf[7] += a1.w;
        }
        u16x8 hi_us, lo_us;
#pragma unroll
        for (int j = 0; j < 8; j++) {
            unsigned short hb = f2b(vf[j]);
            hi_us[j] = hb;
            lo_us[j] = f2b(vf[j] - b2f(hb));
        }
        bf16x8 ahi = __builtin_bit_cast(bf16x8, hi_us);
        bf16x8 alo = __builtin_bit_cast(bf16x8, lo_us);
#pragma unroll
        for (int t = 0; t < 8; t++) {
            bf16x8 b = *reinterpret_cast<const bf16x8*>(wfl + ((t * KC + c) << 9));
            acc[t] = __builtin_amdgcn_mfma_f32_16x16x32_bf16(ahi, b, acc[t], 0, 0, 0);
            acc[t] = __builtin_amdgcn_mfma_f32_16x16x32_bf16(alo, b, acc[t], 0, 0, 0);
        }
    }

    // C/D: col = lane&15, row = (lane>>4)*4 + r
#pragma unroll
    for (int r = 0; r < 4; r++) {
        int orow = rowbase + q * 4 + r;
        if (orow < M) {
            float* op = Out + (size_t)orow * HID;
#pragma unroll
            for (int t = 0; t < 8; t++) {
                int col = t * 16 + m_;
                float bv = flag ? ((const float*)bias)[col]
                                : b2f(((const unsigned short*)bias)[col]);
                float v = acc[t][r] + bv;
                op[col] = v > 0.0f ? v : 0.0f;
            }
        }
    }
}

__global__ void count_nodes_kernel(const int* __restrict__ batch, int n,
                                   int* __restrict__ cnt) {
    int t = blockIdx.x * 256 + threadIdx.x;
    if (t < n) atomicAdd(&cnt[batch[t]], 1);
}

__global__ void pool_kernel(const float* __restrict__ h, const int* __restrict__ batch,
                            float* __restrict__ psum, unsigned int* __restrict__ pmax,
                            int nNodes) {
    int t = blockIdx.x * 256 + threadIdx.x;
    int i = t >> 7;
    if (i >= nNodes) return;
    int f = t & 127;
    int g = batch[i];
    float v = h[(size_t)i * HID + f];
    atomicAdd(&psum[g * HID + f], v);
    atomicMax(&pmax[g * HID + f], __float_as_uint(v));   // h >= 0 post-relu
}

__global__ __launch_bounds__(128) void head_kernel(
    const float* __restrict__ psum, const unsigned int* __restrict__ pmax,
    const int* __restrict__ cnt,
    const void* __restrict__ w1, const void* __restrict__ b1,
    const void* __restrict__ w2, const void* __restrict__ b2,
    void* __restrict__ out, const int* __restrict__ flagp) {
    int g = blockIdx.x;
    int n = threadIdx.x;
    int flag = *flagp;
    __shared__ float repr[2 * HID];
    __shared__ float red[HID];

    float c = (float)cnt[g];
    float inv = 1.0f / fmaxf(c, 1.0f);
    repr[n]       = psum[g * HID + n] * inv;
    repr[HID + n] = __uint_as_float(pmax[g * HID + n]);
    __syncthreads();

    float acc = flag ? ((const float*)b1)[n] : b2f(((const unsigned short*)b1)[n]);
    for (int k = 0; k < 2 * HID; k++) {
        float w = flag ? ((const float*)w1)[k * HID + n]
                       : b2f(((const unsigned short*)w1)[k * HID + n]);
        acc += repr[k] * w;
    }
    acc = fmaxf(acc, 0.0f);

    float w2v = flag ? ((const float*)w2)[n] : b2f(((const unsigned short*)w2)[n]);
    red[n] = acc * w2v;
    __syncthreads();
    for (int s = 64; s > 0; s >>= 1) {
        if (n < s) red[n] += red[n + s];
        __syncthreads();
    }
    if (n == 0) {
        float b2v = flag ? ((const float*)b2)[0] : b2f(((const unsigned short*)b2)[0]);
        float logit = red[0] + b2v;
        float sv = 1.0f / (1.0f + expf(-logit));
        if (flag) ((float*)out)[g] = sv;
        else      ((unsigned short*)out)[g] = f2b(sv);
    }
}

extern "C" void kernel_launch(void* const* d_in, const int* in_sizes, int n_in,
                              void* d_out, int out_size, void* d_ws, size_t ws_size,
                              hipStream_t stream) {
    const int* edge = (const int*)d_in[1];
    const int* srcv = edge;
    const int* dstv = edge + N_EDGES;
    const int* batch = (const int*)d_in[2];

    const void* gw1[3] = {d_in[3], d_in[7], d_in[11]};
    const void* gb1[3] = {d_in[4], d_in[8], d_in[12]};
    const void* gw2[3] = {d_in[5], d_in[9], d_in[13]};
    const void* gb2[3] = {d_in[6], d_in[10], d_in[14]};

    char* ws = (char*)d_ws;
    float* P0 = (float*)ws;                     // h0 (3.2M f32) / h1..h3 (6.4M f32)
    float* P1 = (float*)(ws + 12800000);        // agg0 (3.2M f32)
    float* P2 = (float*)(ws + 25600000);        // mid0 / agg+mid for layers 1-2 (6.4M f32)
    unsigned short* wf[6];
    for (int i = 0; i < 6; i++) wf[i] = (unsigned short*)(ws + 51200000 + (size_t)i * 32768);
    float* psum = (float*)(ws + 51396608);          // 128 KB
    unsigned int* pmax = (unsigned int*)(ws + 51527680); // 128 KB
    int* cnt = (int*)(ws + 51658752);               // 1 KB
    int* flagp = (int*)(ws + 51659776);

    const size_t NEED = 51700000;
    if (ws_size < NEED) {
        unsigned int k = 0;
        while ((((size_t)1) << (k + 1)) <= ws_size && k < 62) k++;
        diag_kernel<<<1, 256, 0, stream>>>((unsigned short*)d_out,
                                           (unsigned short)(0x4000 | (k & 63)));
        return;
    }

    detect_kernel<<<1, 256, 0, stream>>>((const unsigned short*)d_in[0], flagp);

    reorder_w_kernel<<<32, 256, 0, stream>>>(gw1[0], wf[0], 64, 2, flagp);
    reorder_w_kernel<<<64, 256, 0, stream>>>(gw2[0], wf[1], 128, 4, flagp);
    reorder_w_kernel<<<64, 256, 0, stream>>>(gw1[1], wf[2], 128, 4, flagp);
    reorder_w_kernel<<<64, 256, 0, stream>>>(gw2[1], wf[3], 128, 4, flagp);
    reorder_w_kernel<<<64, 256, 0, stream>>>(gw1[2], wf[4], 128, 4, flagp);
    reorder_w_kernel<<<64, 256, 0, stream>>>(gw2[2], wf[5], 128, 4, flagp);

    cvt_x_kernel<<<12500, 256, 0, stream>>>(d_in[0], P0, N_NODES * IN_DIM, flagp);

    const int GEMM_GRID = (N_NODES + 63) / 64;  // 782

    // layer 0 (dim 64 -> 128)
    hipMemsetAsync(P1, 0, 12800000, stream);
    scatter_kernel<<<50000, 256, 0, stream>>>(P0, srcv, dstv, P1, 4);
    gemm_kernel<64, true><<<GEMM_GRID, 256, 0, stream>>>(P0, P1, wf[0], gb1[0], P2, N_NODES, flagp);
    gemm_kernel<128, false><<<GEMM_GRID, 256, 0, stream>>>(P2, nullptr, wf[1], gb2[0], P0, N_NODES, flagp);

    // layers 1,2 (dim 128 -> 128)
    for (int l = 1; l < 3; l++) {
        hipMemsetAsync(P2, 0, 25600000, stream);
        scatter_kernel<<<100000, 256, 0, stream>>>(P0, srcv, dstv, P2, 5);
        gemm_kernel<128, true><<<GEMM_GRID, 256, 0, stream>>>(P0, P2, wf[2 * l], gb1[l], P2, N_NODES, flagp);
        gemm_kernel<128, false><<<GEMM_GRID, 256, 0, stream>>>(P2, nullptr, wf[2 * l + 1], gb2[l], P0, N_NODES, flagp);
    }

    // readout + head
    hipMemsetAsync(psum, 0, 131072, stream);
    hipMemsetAsync(pmax, 0, 131072, stream);
    hipMemsetAsync(cnt, 0, 1024, stream);
    count_nodes_kernel<<<(N_NODES + 255) / 256, 256, 0, stream>>>(batch, N_NODES, cnt);
    pool_kernel<<<25000, 256, 0, stream>>>(P0, batch, psum, pmax, N_NODES);
    head_kernel<<<NUM_GRAPHS, 128, 0, stream>>>(psum, pmax, cnt,
                                                d_in[15], d_in[16], d_in[17], d_in[18],
                                                d_out, flagp);
}

// Round 3
// 750.530 us; speedup vs baseline: 4.9864x; 4.9864x over previous
//
#include <hip/hip_runtime.h>
#include <hip/hip_bf16.h>

#define N_NODES   50000
#define N_EDGES   800000
#define IN_DIM    64
#define HID       128
#define NUM_GRAPHS 256

typedef __bf16 bf16x8 __attribute__((ext_vector_type(8)));
typedef unsigned short u16x8 __attribute__((ext_vector_type(8)));
typedef float f32x4 __attribute__((ext_vector_type(4)));

__device__ __forceinline__ float b2f(unsigned short u) {
    return __uint_as_float(((unsigned int)u) << 16);
}
__device__ __forceinline__ unsigned short f2b(float f) {
    unsigned int x = __float_as_uint(f);
    x = (x + 0x7fffu + ((x >> 16) & 1u)) >> 16;   // RNE
    return (unsigned short)x;
}

// ---- dtype probe (bf16 vs fp32 inputs), kept from R2 ----
__global__ void detect_kernel(const unsigned short* __restrict__ x, int* __restrict__ flag) {
    __shared__ int cnt;
    if (threadIdx.x == 0) cnt = 0;
    __syncthreads();
    int c = 0;
    for (int j = 0; j < 16; j++) {
        unsigned short u = x[2 * (threadIdx.x * 16 + j)];
        int e = (u >> 7) & 0xff;
        if (e <= 100 || e >= 140) c++;
    }
    atomicAdd(&cnt, c);
    __syncthreads();
    if (threadIdx.x == 0) *flag = (cnt > 1024) ? 1 : 0;   // 1 = fp32, 0 = bf16
}

__global__ void diag_kernel(unsigned short* out, unsigned short pat) {
    out[threadIdx.x] = pat;
}

__global__ void cvt_x_kernel(const void* __restrict__ x, float* __restrict__ h, int n,
                             const int* __restrict__ flagp) {
    int t = blockIdx.x * 256 + threadIdx.x;
    if (t >= n) return;
    int flag = *flagp;
    h[t] = flag ? ((const float*)x)[t] : b2f(((const unsigned short*)x)[t]);
}

// ---------------- CSR build (counting sort by dst) ----------------

__global__ void degree_kernel(const int* __restrict__ dst, int* __restrict__ deg) {
    int e = blockIdx.x * 256 + threadIdx.x;
    if (e < N_EDGES) atomicAdd(&deg[dst[e]], 1);
}

__global__ __launch_bounds__(256) void scan_nodes_kernel(const int* __restrict__ deg,
        int* __restrict__ off, int* __restrict__ cursor) {
    __shared__ int partial[256];
    int tid = threadIdx.x;
    const int per = (N_NODES + 255) / 256;   // 196
    int s = tid * per;
    int e = s + per < N_NODES ? s + per : N_NODES;
    int sum = 0;
    for (int i = s; i < e; i++) sum += deg[i];
    partial[tid] = sum;
    __syncthreads();
    if (tid == 0) {
        int run = 0;
        for (int i = 0; i < 256; i++) { int v = partial[i]; partial[i] = run; run += v; }
    }
    __syncthreads();
    int run = partial[tid];
    for (int i = s; i < e; i++) {
        off[i] = run; cursor[i] = run; run += deg[i];
    }
    if (tid == 255) off[N_NODES] = run;
}

__global__ void fill_kernel(const int* __restrict__ src, const int* __restrict__ dst,
                            int* __restrict__ cursor, int* __restrict__ csr) {
    int e = blockIdx.x * 256 + threadIdx.x;
    if (e >= N_EDGES) return;
    int p = atomicAdd(&cursor[dst[e]], 1);
    csr[p] = src[e];
}

// ---------------- gather: z[i] = h[i] + sum_{j->i} h[j] ----------------
// one wave per node; DIM=128: lane holds float2; DIM=64: lane holds float
template <int DIM>
__global__ __launch_bounds__(256) void gather_kernel(const float* __restrict__ h,
        const int* __restrict__ off, const int* __restrict__ csr,
        float* __restrict__ z) {
    int node = blockIdx.x * 4 + (threadIdx.x >> 6);
    if (node >= N_NODES) return;
    int lane = threadIdx.x & 63;
    int s = off[node], e = off[node + 1];
    if constexpr (DIM == 128) {
        const float2* hp = (const float2*)h;
        float2 a = hp[(size_t)node * 64 + lane];
        float bx = 0.0f, by = 0.0f;
        int i = s;
        for (; i + 1 < e; i += 2) {
            int s0 = csr[i], s1 = csr[i + 1];
            float2 v0 = hp[(size_t)s0 * 64 + lane];
            float2 v1 = hp[(size_t)s1 * 64 + lane];
            a.x += v0.x; a.y += v0.y; bx += v1.x; by += v1.y;
        }
        if (i < e) {
            float2 v = hp[(size_t)csr[i] * 64 + lane];
            a.x += v.x; a.y += v.y;
        }
        ((float2*)z)[(size_t)node * 64 + lane] = make_float2(a.x + bx, a.y + by);
    } else {
        float a = h[(size_t)node * 64 + lane];
        float b = 0.0f;
        int i = s;
        for (; i + 1 < e; i += 2) {
            a += h[(size_t)csr[i] * 64 + lane];
            b += h[(size_t)csr[i + 1] * 64 + lane];
        }
        if (i < e) a += h[(size_t)csr[i] * 64 + lane];
        z[(size_t)node * 64 + lane] = a + b;
    }
}

// ---------------- weight reorder into MFMA B-fragment order ----------------
__global__ void reorder_w_kernel(const void* __restrict__ W, unsigned short* __restrict__ Wf,
                                 int K, int KC, const int* __restrict__ flagp) {
    int idx = blockIdx.x * 256 + threadIdx.x;
    if (idx >= K * 128) return;
    int flag = *flagp;
    int j  = idx & 7;
    int l  = (idx >> 3) & 63;
    int tc = idx >> 9;
    int c  = tc % KC;
    int t  = tc / KC;
    int k  = c * 32 + (l >> 4) * 8 + j;
    int n  = t * 16 + (l & 15);
    Wf[idx] = flag ? f2b(((const float*)W)[k * 128 + n])
                   : ((const unsigned short*)W)[k * 128 + n];
}

// ---------------- GEMM: Out[M,128] = relu(Z[M,K] @ W + bias), bf16 hi/lo split A ----------------
template <int K>
__global__ __launch_bounds__(256) void gemm_kernel(
    const float* __restrict__ Z,
    const unsigned short* __restrict__ Wf, const void* __restrict__ bias,
    float* __restrict__ Out, int M, const int* __restrict__ flagp) {
    constexpr int KC = K / 32;
    int flag = *flagp;
    int wave = threadIdx.x >> 6;
    int lane = threadIdx.x & 63;
    int m_ = lane & 15;
    int q  = lane >> 4;
    int rowbase = blockIdx.x * 64 + wave * 16;
    int row  = rowbase + m_;
    int rowc = row < M ? row : (M - 1);

    const float* zrow = Z + (size_t)rowc * K + q * 8;
    const unsigned short* wfl = Wf + lane * 8;

    f32x4 acc[8];
#pragma unroll
    for (int t = 0; t < 8; t++) acc[t] = (f32x4)(0.0f);

#pragma unroll
    for (int c = 0; c < KC; c++) {
        float4 h0 = *(const float4*)(zrow + c * 32);
        float4 h1 = *(const float4*)(zrow + c * 32 + 4);
        float vf[8] = {h0.x, h0.y, h0.z, h0.w, h1.x, h1.y, h1.z, h1.w};
        u16x8 hi_us, lo_us;
#pragma unroll
        for (int j = 0; j < 8; j++) {
            unsigned short hb = f2b(vf[j]);
            hi_us[j] = hb;
            lo_us[j] = f2b(vf[j] - b2f(hb));
        }
        bf16x8 ahi = __builtin_bit_cast(bf16x8, hi_us);
        bf16x8 alo = __builtin_bit_cast(bf16x8, lo_us);
#pragma unroll
        for (int t = 0; t < 8; t++) {
            bf16x8 b = *reinterpret_cast<const bf16x8*>(wfl + ((t * KC + c) << 9));
            acc[t] = __builtin_amdgcn_mfma_f32_16x16x32_bf16(ahi, b, acc[t], 0, 0, 0);
            acc[t] = __builtin_amdgcn_mfma_f32_16x16x32_bf16(alo, b, acc[t], 0, 0, 0);
        }
    }

    // C/D: col = lane&15, row = (lane>>4)*4 + r
#pragma unroll
    for (int r = 0; r < 4; r++) {
        int orow = rowbase + q * 4 + r;
        if (orow < M) {
            float* op = Out + (size_t)orow * HID;
#pragma unroll
            for (int t = 0; t < 8; t++) {
                int col = t * 16 + m_;
                float bv = flag ? ((const float*)bias)[col]
                                : b2f(((const unsigned short*)bias)[col]);
                float v = acc[t][r] + bv;
                op[col] = v > 0.0f ? v : 0.0f;
            }
        }
    }
}

// ---------------- pooling: batch_idx is SORTED -> per-graph contiguous ranges ----------------

__global__ void count_graphs_kernel(const int* __restrict__ batch, int* __restrict__ gcnt) {
    int t = blockIdx.x * 256 + threadIdx.x;
    if (t < N_NODES) atomicAdd(&gcnt[batch[t]], 1);
}

__global__ void scan_graphs_kernel(const int* __restrict__ gcnt, int* __restrict__ gstart) {
    if (threadIdx.x == 0) {
        int run = 0;
        for (int g = 0; g < NUM_GRAPHS; g++) { gstart[g] = run; run += gcnt[g]; }
        gstart[NUM_GRAPHS] = run;
    }
}

__global__ __launch_bounds__(128) void pool_kernel(const float* __restrict__ h,
        const int* __restrict__ gstart, float* __restrict__ psum, float* __restrict__ pmax) {
    int g = blockIdx.x;
    int f = threadIdx.x;
    int s = gstart[g], e = gstart[g + 1];
    float sum = 0.0f, mx = 0.0f;   // h >= 0 post-relu; empty graph -> 0 matches ref
    for (int i = s; i < e; i++) {
        float v = h[(size_t)i * HID + f];
        sum += v;
        mx = fmaxf(mx, v);
    }
    psum[g * HID + f] = sum;
    pmax[g * HID + f] = mx;
}

// ---------------- head ----------------
__global__ __launch_bounds__(128) void head_kernel(
    const float* __restrict__ psum, const float* __restrict__ pmax,
    const int* __restrict__ gstart,
    const void* __restrict__ w1, const void* __restrict__ b1,
    const void* __restrict__ w2, const void* __restrict__ b2,
    void* __restrict__ out, const int* __restrict__ flagp) {
    int g = blockIdx.x;
    int n = threadIdx.x;
    int flag = *flagp;
    __shared__ float repr[2 * HID];
    __shared__ float red[HID];

    float c = (float)(gstart[g + 1] - gstart[g]);
    float inv = 1.0f / fmaxf(c, 1.0f);
    repr[n]       = psum[g * HID + n] * inv;
    repr[HID + n] = pmax[g * HID + n];
    __syncthreads();

    float acc = flag ? ((const float*)b1)[n] : b2f(((const unsigned short*)b1)[n]);
    for (int k = 0; k < 2 * HID; k++) {
        float w = flag ? ((const float*)w1)[k * HID + n]
                       : b2f(((const unsigned short*)w1)[k * HID + n]);
        acc += repr[k] * w;
    }
    acc = fmaxf(acc, 0.0f);

    float w2v = flag ? ((const float*)w2)[n] : b2f(((const unsigned short*)w2)[n]);
    red[n] = acc * w2v;
    __syncthreads();
    for (int s = 64; s > 0; s >>= 1) {
        if (n < s) red[n] += red[n + s];
        __syncthreads();
    }
    if (n == 0) {
        float b2v = flag ? ((const float*)b2)[0] : b2f(((const unsigned short*)b2)[0]);
        float logit = red[0] + b2v;
        float sv = 1.0f / (1.0f + expf(-logit));
        if (flag) ((float*)out)[g] = sv;
        else      ((unsigned short*)out)[g] = f2b(sv);
    }
}

extern "C" void kernel_launch(void* const* d_in, const int* in_sizes, int n_in,
                              void* d_out, int out_size, void* d_ws, size_t ws_size,
                              hipStream_t stream) {
    const int* edge = (const int*)d_in[1];
    const int* srcv = edge;
    const int* dstv = edge + N_EDGES;
    const int* batch = (const int*)d_in[2];

    const void* gw1[3] = {d_in[3], d_in[7], d_in[11]};
    const void* gb1[3] = {d_in[4], d_in[8], d_in[12]};
    const void* gw2[3] = {d_in[5], d_in[9], d_in[13]};
    const void* gb2[3] = {d_in[6], d_in[10], d_in[14]};

    char* ws = (char*)d_ws;
    float* A = (float*)ws;                         // 25.6 MB
    float* B = (float*)(ws + 25600000);            // 25.6 MB
    int* off    = (int*)(ws + 51200000);           // (N+1) ints, pad to 200704
    int* cursor = (int*)(ws + 51400704);           // N ints
    int* deg    = (int*)(ws + 51601408);           // N ints
    int* csr    = (int*)(ws + 51802112);           // 800000 ints = 3.2 MB
    unsigned short* wf[6];
    for (int i = 0; i < 6; i++) wf[i] = (unsigned short*)(ws + 55002112 + (size_t)i * 32768);
    float* psum  = (float*)(ws + 55198720);        // 128 KB
    float* pmax  = (float*)(ws + 55329792);        // 128 KB
    int* gcnt    = (int*)(ws + 55460864);          // 1 KB
    int* gstart  = (int*)(ws + 55461888);          // 1028 B (pad 2 KB)
    int* flagp   = (int*)(ws + 55463936);

    const size_t NEED = 55500000;
    if (ws_size < NEED) {
        unsigned int k = 0;
        while ((((size_t)1) << (k + 1)) <= ws_size && k < 62) k++;
        diag_kernel<<<1, 256, 0, stream>>>((unsigned short*)d_out,
                                           (unsigned short)(0x4000 | (k & 63)));
        return;
    }

    detect_kernel<<<1, 256, 0, stream>>>((const unsigned short*)d_in[0], flagp);

    hipMemsetAsync(deg, 0, N_NODES * 4, stream);
    hipMemsetAsync(gcnt, 0, NUM_GRAPHS * 4, stream);

    reorder_w_kernel<<<32, 256, 0, stream>>>(gw1[0], wf[0], 64, 2, flagp);
    reorder_w_kernel<<<64, 256, 0, stream>>>(gw2[0], wf[1], 128, 4, flagp);
    reorder_w_kernel<<<64, 256, 0, stream>>>(gw1[1], wf[2], 128, 4, flagp);
    reorder_w_kernel<<<64, 256, 0, stream>>>(gw2[1], wf[3], 128, 4, flagp);
    reorder_w_kernel<<<64, 256, 0, stream>>>(gw1[2], wf[4], 128, 4, flagp);
    reorder_w_kernel<<<64, 256, 0, stream>>>(gw2[2], wf[5], 128, 4, flagp);

    // CSR build (once, reused for all 3 layers)
    degree_kernel<<<3125, 256, 0, stream>>>(dstv, deg);
    scan_nodes_kernel<<<1, 256, 0, stream>>>(deg, off, cursor);
    fill_kernel<<<3125, 256, 0, stream>>>(srcv, dstv, cursor, csr);

    // graph ranges (batch sorted)
    count_graphs_kernel<<<196, 256, 0, stream>>>(batch, gcnt);
    scan_graphs_kernel<<<1, 64, 0, stream>>>(gcnt, gstart);

    // h0 = float(x) -> A (64-dim)
    cvt_x_kernel<<<12500, 256, 0, stream>>>(d_in[0], A, N_NODES * IN_DIM, flagp);

    const int GEMM_GRID = (N_NODES + 63) / 64;  // 782
    const int GATHER_GRID = (N_NODES + 3) / 4;  // 12500

    // layer 0: 64 -> 128
    gather_kernel<64><<<GATHER_GRID, 256, 0, stream>>>(A, off, csr, B);
    gemm_kernel<64><<<GEMM_GRID, 256, 0, stream>>>(B, wf[0], gb1[0], A, N_NODES, flagp);
    gemm_kernel<128><<<GEMM_GRID, 256, 0, stream>>>(A, wf[1], gb2[0], B, N_NODES, flagp);

    // layers 1,2: 128 -> 128  (gemm A->A in-place is safe: each wave reads only its
    // own 16 rows in the K-loop, then writes the same rows in the epilogue)
    for (int l = 1; l < 3; l++) {
        gather_kernel<128><<<GATHER_GRID, 256, 0, stream>>>(B, off, csr, A);
        gemm_kernel<128><<<GEMM_GRID, 256, 0, stream>>>(A, wf[2 * l], gb1[l], A, N_NODES, flagp);
        gemm_kernel<128><<<GEMM_GRID, 256, 0, stream>>>(A, wf[2 * l + 1], gb2[l], B, N_NODES, flagp);
    }

    // readout + head
    pool_kernel<<<NUM_GRAPHS, 128, 0, stream>>>(B, gstart, psum, pmax);
    head_kernel<<<NUM_GRAPHS, 128, 0, stream>>>(psum, pmax, gstart,
                                                d_in[15], d_in[16], d_in[17], d_in[18],
                                                d_out, flagp);
}

// Round 4
// 532.754 us; speedup vs baseline: 7.0248x; 1.4088x over previous
//
#include <hip/hip_runtime.h>
#include <hip/hip_bf16.h>

#define N_NODES   50000
#define N_EDGES   800000
#define IN_DIM    64
#define HID       128
#define NUM_GRAPHS 256

typedef __bf16 bf16x8 __attribute__((ext_vector_type(8)));
typedef unsigned short u16x8 __attribute__((ext_vector_type(8)));
typedef float f32x4 __attribute__((ext_vector_type(4)));

__device__ __forceinline__ float b2f(unsigned short u) {
    return __uint_as_float(((unsigned int)u) << 16);
}
__device__ __forceinline__ unsigned short f2b(float f) {
    unsigned int x = __float_as_uint(f);
    x = (x + 0x7fffu + ((x >> 16) & 1u)) >> 16;   // RNE
    return (unsigned short)x;
}

// ---- dtype probe (bf16 vs fp32 inputs) ----
__global__ void detect_kernel(const unsigned short* __restrict__ x, int* __restrict__ flag) {
    __shared__ int cnt;
    if (threadIdx.x == 0) cnt = 0;
    __syncthreads();
    int c = 0;
    for (int j = 0; j < 16; j++) {
        unsigned short u = x[2 * (threadIdx.x * 16 + j)];
        int e = (u >> 7) & 0xff;
        if (e <= 100 || e >= 140) c++;
    }
    atomicAdd(&cnt, c);
    __syncthreads();
    if (threadIdx.x == 0) *flag = (cnt > 1024) ? 1 : 0;   // 1 = fp32, 0 = bf16
}

__global__ void diag_kernel(unsigned short* out, unsigned short pat) {
    out[threadIdx.x] = pat;
}

__global__ void cvt_x_kernel(const void* __restrict__ x, float* __restrict__ h, int n,
                             const int* __restrict__ flagp) {
    int t = blockIdx.x * 256 + threadIdx.x;
    if (t >= n) return;
    int flag = *flagp;
    h[t] = flag ? ((const float*)x)[t] : b2f(((const unsigned short*)x)[t]);
}

// ---------------- CSR build (counting sort by dst) ----------------

__global__ void degree_kernel(const int* __restrict__ dst, int* __restrict__ deg) {
    int e = blockIdx.x * 256 + threadIdx.x;
    if (e < N_EDGES) atomicAdd(&deg[dst[e]], 1);
}

// phase 1: per-block sums of deg (196 blocks x 256)
__global__ __launch_bounds__(256) void scan1_kernel(const int* __restrict__ deg,
                                                    int* __restrict__ partial) {
    __shared__ int s[256];
    int i = blockIdx.x * 256 + threadIdx.x;
    s[threadIdx.x] = (i < N_NODES) ? deg[i] : 0;
    __syncthreads();
    for (int d = 128; d > 0; d >>= 1) {
        if (threadIdx.x < d) s[threadIdx.x] += s[threadIdx.x + d];
        __syncthreads();
    }
    if (threadIdx.x == 0) partial[blockIdx.x] = s[0];
}

// phase 2: scan the 196 block sums (1 block)
__global__ __launch_bounds__(256) void scan2_kernel(const int* __restrict__ partial,
                                                    int* __restrict__ pscan,
                                                    int* __restrict__ off, int nblk) {
    __shared__ int s[256];
    int tid = threadIdx.x;
    int v = (tid < nblk) ? partial[tid] : 0;
    s[tid] = v;
    __syncthreads();
    for (int d = 1; d < 256; d <<= 1) {
        int t = (tid >= d) ? s[tid - d] : 0;
        __syncthreads();
        s[tid] += t;
        __syncthreads();
    }
    if (tid < nblk) pscan[tid] = s[tid] - v;   // exclusive
    if (tid == 255) off[N_NODES] = s[255];     // total
}

// phase 3: per-block exclusive scan + base -> off, cursor
__global__ __launch_bounds__(256) void scan3_kernel(const int* __restrict__ deg,
                                                    const int* __restrict__ pscan,
                                                    int* __restrict__ off,
                                                    int* __restrict__ cursor) {
    __shared__ int s[256];
    int i = blockIdx.x * 256 + threadIdx.x;
    int tid = threadIdx.x;
    int v = (i < N_NODES) ? deg[i] : 0;
    s[tid] = v;
    __syncthreads();
    for (int d = 1; d < 256; d <<= 1) {
        int t = (tid >= d) ? s[tid - d] : 0;
        __syncthreads();
        s[tid] += t;
        __syncthreads();
    }
    if (i < N_NODES) {
        int o = pscan[blockIdx.x] + s[tid] - v;
        off[i] = o;
        cursor[i] = o;
    }
}

__global__ void fill_kernel(const int* __restrict__ src, const int* __restrict__ dst,
                            int* __restrict__ cursor, int* __restrict__ csr) {
    int e = blockIdx.x * 256 + threadIdx.x;
    if (e >= N_EDGES) return;
    int p = atomicAdd(&cursor[dst[e]], 1);
    csr[p] = src[e];
}

// graph ranges via boundary detection (batch sorted)
__global__ void gbounds_kernel(const int* __restrict__ batch, int* __restrict__ gstart) {
    int i = blockIdx.x * 256 + threadIdx.x;
    if (i >= N_NODES) return;
    int b1 = batch[i];
    int b0 = (i == 0) ? -1 : batch[i - 1];
    for (int g = b0 + 1; g <= b1; g++) gstart[g] = i;
    if (i == N_NODES - 1)
        for (int g = b1 + 1; g <= NUM_GRAPHS; g++) gstart[g] = N_NODES;
}

// ---------------- gather: z[i] = h[i] + sum_{j->i} h[j], 4-way unrolled ----------------
template <int DIM>
__global__ __launch_bounds__(256) void gather_kernel(const float* __restrict__ h,
        const int* __restrict__ off, const int* __restrict__ csr,
        float* __restrict__ z) {
    int node = blockIdx.x * 4 + (threadIdx.x >> 6);
    if (node >= N_NODES) return;
    int lane = threadIdx.x & 63;
    int s = off[node], e = off[node + 1];
    if constexpr (DIM == 128) {
        const float2* hp = (const float2*)h;
        float2 a0 = hp[(size_t)node * 64 + lane];
        float2 a1 = {0.f, 0.f}, a2 = {0.f, 0.f}, a3 = {0.f, 0.f};
        int i = s;
        for (; i + 3 < e; i += 4) {
            int s0 = csr[i], s1 = csr[i + 1], s2 = csr[i + 2], s3 = csr[i + 3];
            float2 v0 = hp[(size_t)s0 * 64 + lane];
            float2 v1 = hp[(size_t)s1 * 64 + lane];
            float2 v2 = hp[(size_t)s2 * 64 + lane];
            float2 v3 = hp[(size_t)s3 * 64 + lane];
            a0.x += v0.x; a0.y += v0.y;
            a1.x += v1.x; a1.y += v1.y;
            a2.x += v2.x; a2.y += v2.y;
            a3.x += v3.x; a3.y += v3.y;
        }
        for (; i < e; i++) {
            float2 v = hp[(size_t)csr[i] * 64 + lane];
            a0.x += v.x; a0.y += v.y;
        }
        ((float2*)z)[(size_t)node * 64 + lane] =
            make_float2(a0.x + a1.x + a2.x + a3.x, a0.y + a1.y + a2.y + a3.y);
    } else {
        float a0 = h[(size_t)node * 64 + lane];
        float a1 = 0.f, a2 = 0.f, a3 = 0.f;
        int i = s;
        for (; i + 3 < e; i += 4) {
            a0 += h[(size_t)csr[i] * 64 + lane];
            a1 += h[(size_t)csr[i + 1] * 64 + lane];
            a2 += h[(size_t)csr[i + 2] * 64 + lane];
            a3 += h[(size_t)csr[i + 3] * 64 + lane];
        }
        for (; i < e; i++) a0 += h[(size_t)csr[i] * 64 + lane];
        z[(size_t)node * 64 + lane] = a0 + a1 + a2 + a3;
    }
}

// ---------------- merged weight reorder (all 6 matrices, one launch) ----------------
__global__ void reorder_all_kernel(const void* w0, const void* w1, const void* w2,
                                   const void* w3, const void* w4, const void* w5,
                                   unsigned short* __restrict__ wfbase,
                                   const int* __restrict__ flagp) {
    int b = blockIdx.x;
    int mat, boff;
    if (b < 32) { mat = 0; boff = b; }
    else { mat = 1 + (b - 32) / 64; boff = (b - 32) % 64; }
    const void* W = mat == 0 ? w0 : mat == 1 ? w1 : mat == 2 ? w2
                  : mat == 3 ? w3 : mat == 4 ? w4 : w5;
    int KC = (mat == 0) ? 2 : 4;
    int flag = *flagp;
    int idx = boff * 256 + threadIdx.x;
    int j  = idx & 7;
    int l  = (idx >> 3) & 63;
    int tc = idx >> 9;
    int c  = tc % KC;
    int t  = tc / KC;
    int k  = c * 32 + (l >> 4) * 8 + j;
    int n  = t * 16 + (l & 15);
    unsigned short v = flag ? f2b(((const float*)W)[k * 128 + n])
                            : ((const unsigned short*)W)[k * 128 + n];
    wfbase[mat * 16384 + idx] = v;
}

// ---------------- GEMM: Out[M,128] = relu(Z[M,K] @ W + bias), bf16 hi/lo split A ----------------
template <int K>
__global__ __launch_bounds__(256) void gemm_kernel(
    const float* __restrict__ Z,
    const unsigned short* __restrict__ Wf, const void* __restrict__ bias,
    float* __restrict__ Out, int M, const int* __restrict__ flagp) {
    constexpr int KC = K / 32;
    int flag = *flagp;
    int wave = threadIdx.x >> 6;
    int lane = threadIdx.x & 63;
    int m_ = lane & 15;
    int q  = lane >> 4;
    int rowbase = blockIdx.x * 64 + wave * 16;
    int row  = rowbase + m_;
    int rowc = row < M ? row : (M - 1);

    const float* zrow = Z + (size_t)rowc * K + q * 8;
    const unsigned short* wfl = Wf + lane * 8;

    f32x4 acc[8];
#pragma unroll
    for (int t = 0; t < 8; t++) acc[t] = (f32x4)(0.0f);

#pragma unroll
    for (int c = 0; c < KC; c++) {
        float4 h0 = *(const float4*)(zrow + c * 32);
        float4 h1 = *(const float4*)(zrow + c * 32 + 4);
        float vf[8] = {h0.x, h0.y, h0.z, h0.w, h1.x, h1.y, h1.z, h1.w};
        u16x8 hi_us, lo_us;
#pragma unroll
        for (int j = 0; j < 8; j++) {
            unsigned short hb = f2b(vf[j]);
            hi_us[j] = hb;
            lo_us[j] = f2b(vf[j] - b2f(hb));
        }
        bf16x8 ahi = __builtin_bit_cast(bf16x8, hi_us);
        bf16x8 alo = __builtin_bit_cast(bf16x8, lo_us);
#pragma unroll
        for (int t = 0; t < 8; t++) {
            bf16x8 b = *reinterpret_cast<const bf16x8*>(wfl + ((t * KC + c) << 9));
            acc[t] = __builtin_amdgcn_mfma_f32_16x16x32_bf16(ahi, b, acc[t], 0, 0, 0);
            acc[t] = __builtin_amdgcn_mfma_f32_16x16x32_bf16(alo, b, acc[t], 0, 0, 0);
        }
    }

    // C/D: col = lane&15, row = (lane>>4)*4 + r
#pragma unroll
    for (int r = 0; r < 4; r++) {
        int orow = rowbase + q * 4 + r;
        if (orow < M) {
            float* op = Out + (size_t)orow * HID;
#pragma unroll
            for (int t = 0; t < 8; t++) {
                int col = t * 16 + m_;
                float bv = flag ? ((const float*)bias)[col]
                                : b2f(((const unsigned short*)bias)[col]);
                float v = acc[t][r] + bv;
                op[col] = v > 0.0f ? v : 0.0f;
            }
        }
    }
}

// ---------------- pooling over contiguous per-graph ranges ----------------
__global__ __launch_bounds__(128) void pool_kernel(const float* __restrict__ h,
        const int* __restrict__ gstart, float* __restrict__ psum, float* __restrict__ pmax) {
    int g = blockIdx.x;
    int f = threadIdx.x;
    int s = gstart[g], e = gstart[g + 1];
    float sum = 0.0f, mx = 0.0f;   // h >= 0 post-relu; empty graph -> 0 matches ref
    for (int i = s; i < e; i++) {
        float v = h[(size_t)i * HID + f];
        sum += v;
        mx = fmaxf(mx, v);
    }
    psum[g * HID + f] = sum;
    pmax[g * HID + f] = mx;
}

// ---------------- head ----------------
__global__ __launch_bounds__(128) void head_kernel(
    const float* __restrict__ psum, const float* __restrict__ pmax,
    const int* __restrict__ gstart,
    const void* __restrict__ w1, const void* __restrict__ b1,
    const void* __restrict__ w2, const void* __restrict__ b2,
    void* __restrict__ out, const int* __restrict__ flagp) {
    int g = blockIdx.x;
    int n = threadIdx.x;
    int flag = *flagp;
    __shared__ float repr[2 * HID];
    __shared__ float red[HID];

    float c = (float)(gstart[g + 1] - gstart[g]);
    float inv = 1.0f / fmaxf(c, 1.0f);
    repr[n]       = psum[g * HID + n] * inv;
    repr[HID + n] = pmax[g * HID + n];
    __syncthreads();

    float acc = flag ? ((const float*)b1)[n] : b2f(((const unsigned short*)b1)[n]);
    for (int k = 0; k < 2 * HID; k++) {
        float w = flag ? ((const float*)w1)[k * HID + n]
                       : b2f(((const unsigned short*)w1)[k * HID + n]);
        acc += repr[k] * w;
    }
    acc = fmaxf(acc, 0.0f);

    float w2v = flag ? ((const float*)w2)[n] : b2f(((const unsigned short*)w2)[n]);
    red[n] = acc * w2v;
    __syncthreads();
    for (int s = 64; s > 0; s >>= 1) {
        if (n < s) red[n] += red[n + s];
        __syncthreads();
    }
    if (n == 0) {
        float b2v = flag ? ((const float*)b2)[0] : b2f(((const unsigned short*)b2)[0]);
        float logit = red[0] + b2v;
        float sv = 1.0f / (1.0f + expf(-logit));
        if (flag) ((float*)out)[g] = sv;
        else      ((unsigned short*)out)[g] = f2b(sv);
    }
}

extern "C" void kernel_launch(void* const* d_in, const int* in_sizes, int n_in,
                              void* d_out, int out_size, void* d_ws, size_t ws_size,
                              hipStream_t stream) {
    const int* edge = (const int*)d_in[1];
    const int* srcv = edge;
    const int* dstv = edge + N_EDGES;
    const int* batch = (const int*)d_in[2];

    char* ws = (char*)d_ws;
    float* A = (float*)ws;                         // 25.6 MB
    float* B = (float*)(ws + 25600000);            // 25.6 MB
    int* off    = (int*)(ws + 51200000);           // 50001 ints, pad 200704
    int* cursor = (int*)(ws + 51400704);
    int* deg    = (int*)(ws + 51601408);
    int* csr    = (int*)(ws + 51802112);           // 3.2 MB
    unsigned short* wfbase = (unsigned short*)(ws + 55002112);  // 6 x 32 KB
    float* psum  = (float*)(ws + 55198720);        // 128 KB
    float* pmax  = (float*)(ws + 55329792);        // 128 KB
    int* partial = (int*)(ws + 55460864);          // 1 KB
    int* pscan   = (int*)(ws + 55461888);          // 1 KB
    int* gstart  = (int*)(ws + 55462912);          // pad 2 KB
    int* flagp   = (int*)(ws + 55464960);

    const size_t NEED = 55500000;
    if (ws_size < NEED) {
        unsigned int k = 0;
        while ((((size_t)1) << (k + 1)) <= ws_size && k < 62) k++;
        diag_kernel<<<1, 256, 0, stream>>>((unsigned short*)d_out,
                                           (unsigned short)(0x4000 | (k & 63)));
        return;
    }

    detect_kernel<<<1, 256, 0, stream>>>((const unsigned short*)d_in[0], flagp);
    hipMemsetAsync(deg, 0, N_NODES * 4, stream);

    reorder_all_kernel<<<352, 256, 0, stream>>>(d_in[3], d_in[5], d_in[7], d_in[9],
                                                d_in[11], d_in[13], wfbase, flagp);
    // wf order: [0]=gin0_w1(K64), [1]=gin0_w2, [2]=gin1_w1, [3]=gin1_w2, [4]=gin2_w1, [5]=gin2_w2

    // CSR build (once, reused for all 3 layers)
    degree_kernel<<<3125, 256, 0, stream>>>(dstv, deg);
    const int NBLK = (N_NODES + 255) / 256;   // 196
    scan1_kernel<<<NBLK, 256, 0, stream>>>(deg, partial);
    scan2_kernel<<<1, 256, 0, stream>>>(partial, pscan, off, NBLK);
    scan3_kernel<<<NBLK, 256, 0, stream>>>(deg, pscan, off, cursor);
    fill_kernel<<<3125, 256, 0, stream>>>(srcv, dstv, cursor, csr);

    gbounds_kernel<<<NBLK, 256, 0, stream>>>(batch, gstart);

    cvt_x_kernel<<<12500, 256, 0, stream>>>(d_in[0], A, N_NODES * IN_DIM, flagp);

    const int GEMM_GRID = (N_NODES + 63) / 64;  // 782
    const int GATHER_GRID = (N_NODES + 3) / 4;  // 12500

    // layer 0: 64 -> 128
    gather_kernel<64><<<GATHER_GRID, 256, 0, stream>>>(A, off, csr, B);
    gemm_kernel<64><<<GEMM_GRID, 256, 0, stream>>>(B, wfbase + 0 * 16384, d_in[4], A, N_NODES, flagp);
    gemm_kernel<128><<<GEMM_GRID, 256, 0, stream>>>(A, wfbase + 1 * 16384, d_in[6], B, N_NODES, flagp);

    // layers 1,2: 128 -> 128 (in-place gemm A->A is safe: waves read only their own rows)
    for (int l = 1; l < 3; l++) {
        gather_kernel<128><<<GATHER_GRID, 256, 0, stream>>>(B, off, csr, A);
        gemm_kernel<128><<<GEMM_GRID, 256, 0, stream>>>(A, wfbase + (2 * l) * 16384,
                                                        d_in[4 + 4 * l], A, N_NODES, flagp);
        gemm_kernel<128><<<GEMM_GRID, 256, 0, stream>>>(A, wfbase + (2 * l + 1) * 16384,
                                                        d_in[6 + 4 * l], B, N_NODES, flagp);
    }

    // readout + head
    pool_kernel<<<NUM_GRAPHS, 128, 0, stream>>>(B, gstart, psum, pmax);
    head_kernel<<<NUM_GRAPHS, 128, 0, stream>>>(psum, pmax, gstart,
                                                d_in[15], d_in[16], d_in[17], d_in[18],
                                                d_out, flagp);
}

// Round 5
// 480.091 us; speedup vs baseline: 7.7953x; 1.1097x over previous
//
#include <hip/hip_runtime.h>
#include <hip/hip_bf16.h>

#define N_NODES   50000
#define N_EDGES   800000
#define IN_DIM    64
#define HID       128
#define NUM_GRAPHS 256

typedef __bf16 bf16x8 __attribute__((ext_vector_type(8)));
typedef unsigned short u16x8 __attribute__((ext_vector_type(8)));
typedef float f32x4 __attribute__((ext_vector_type(4)));

__device__ __forceinline__ float b2f(unsigned short u) {
    return __uint_as_float(((unsigned int)u) << 16);
}
__device__ __forceinline__ unsigned short f2b(float f) {
    unsigned int x = __float_as_uint(f);
    x = (x + 0x7fffu + ((x >> 16) & 1u)) >> 16;   // RNE
    return (unsigned short)x;
}

// ---- dtype probe (bf16 vs fp32 inputs) ----
__global__ void detect_kernel(const unsigned short* __restrict__ x, int* __restrict__ flag) {
    __shared__ int cnt;
    if (threadIdx.x == 0) cnt = 0;
    __syncthreads();
    int c = 0;
    for (int j = 0; j < 16; j++) {
        unsigned short u = x[2 * (threadIdx.x * 16 + j)];
        int e = (u >> 7) & 0xff;
        if (e <= 100 || e >= 140) c++;
    }
    atomicAdd(&cnt, c);
    __syncthreads();
    if (threadIdx.x == 0) *flag = (cnt > 1024) ? 1 : 0;   // 1 = fp32, 0 = bf16
}

__global__ void diag_kernel(unsigned short* out, unsigned short pat) {
    out[threadIdx.x] = pat;
}

__global__ void cvt_x_kernel(const void* __restrict__ x, float* __restrict__ h, int n,
                             const int* __restrict__ flagp) {
    int t = blockIdx.x * 256 + threadIdx.x;
    if (t >= n) return;
    int flag = *flagp;
    h[t] = flag ? ((const float*)x)[t] : b2f(((const unsigned short*)x)[t]);
}

// ---------------- CSR build (counting sort by dst) ----------------

__global__ void degree_kernel(const int* __restrict__ dst, int* __restrict__ deg) {
    int e = blockIdx.x * 256 + threadIdx.x;
    if (e < N_EDGES) atomicAdd(&deg[dst[e]], 1);
}

__global__ __launch_bounds__(256) void scan1_kernel(const int* __restrict__ deg,
                                                    int* __restrict__ partial) {
    __shared__ int s[256];
    int i = blockIdx.x * 256 + threadIdx.x;
    s[threadIdx.x] = (i < N_NODES) ? deg[i] : 0;
    __syncthreads();
    for (int d = 128; d > 0; d >>= 1) {
        if (threadIdx.x < d) s[threadIdx.x] += s[threadIdx.x + d];
        __syncthreads();
    }
    if (threadIdx.x == 0) partial[blockIdx.x] = s[0];
}

__global__ __launch_bounds__(256) void scan2_kernel(const int* __restrict__ partial,
                                                    int* __restrict__ pscan,
                                                    int* __restrict__ off, int nblk) {
    __shared__ int s[256];
    int tid = threadIdx.x;
    int v = (tid < nblk) ? partial[tid] : 0;
    s[tid] = v;
    __syncthreads();
    for (int d = 1; d < 256; d <<= 1) {
        int t = (tid >= d) ? s[tid - d] : 0;
        __syncthreads();
        s[tid] += t;
        __syncthreads();
    }
    if (tid < nblk) pscan[tid] = s[tid] - v;   // exclusive
    if (tid == 255) off[N_NODES] = s[255];     // total
}

__global__ __launch_bounds__(256) void scan3_kernel(const int* __restrict__ deg,
                                                    const int* __restrict__ pscan,
                                                    int* __restrict__ off,
                                                    int* __restrict__ cursor) {
    __shared__ int s[256];
    int i = blockIdx.x * 256 + threadIdx.x;
    int tid = threadIdx.x;
    int v = (i < N_NODES) ? deg[i] : 0;
    s[tid] = v;
    __syncthreads();
    for (int d = 1; d < 256; d <<= 1) {
        int t = (tid >= d) ? s[tid - d] : 0;
        __syncthreads();
        s[tid] += t;
        __syncthreads();
    }
    if (i < N_NODES) {
        int o = pscan[blockIdx.x] + s[tid] - v;
        off[i] = o;
        cursor[i] = o;
    }
}

__global__ void fill_kernel(const int* __restrict__ src, const int* __restrict__ dst,
                            int* __restrict__ cursor, int* __restrict__ csr) {
    int e = blockIdx.x * 256 + threadIdx.x;
    if (e >= N_EDGES) return;
    int p = atomicAdd(&cursor[dst[e]], 1);
    csr[p] = src[e];
}

__global__ void gbounds_kernel(const int* __restrict__ batch, int* __restrict__ gstart) {
    int i = blockIdx.x * 256 + threadIdx.x;
    if (i >= N_NODES) return;
    int b1 = batch[i];
    int b0 = (i == 0) ? -1 : batch[i - 1];
    for (int g = b0 + 1; g <= b1; g++) gstart[g] = i;
    if (i == N_NODES - 1)
        for (int g = b1 + 1; g <= NUM_GRAPHS; g++) gstart[g] = N_NODES;
}

// ---------------- gather: z[i] = h[i] + sum_{j->i} h[j], 4-way unrolled ----------------
template <int DIM>
__global__ __launch_bounds__(256) void gather_kernel(const float* __restrict__ h,
        const int* __restrict__ off, const int* __restrict__ csr,
        float* __restrict__ z) {
    int node = blockIdx.x * 4 + (threadIdx.x >> 6);
    if (node >= N_NODES) return;
    int lane = threadIdx.x & 63;
    int s = off[node], e = off[node + 1];
    if constexpr (DIM == 128) {
        const float2* hp = (const float2*)h;
        float2 a0 = hp[(size_t)node * 64 + lane];
        float2 a1 = {0.f, 0.f}, a2 = {0.f, 0.f}, a3 = {0.f, 0.f};
        int i = s;
        for (; i + 3 < e; i += 4) {
            int s0 = csr[i], s1 = csr[i + 1], s2 = csr[i + 2], s3 = csr[i + 3];
            float2 v0 = hp[(size_t)s0 * 64 + lane];
            float2 v1 = hp[(size_t)s1 * 64 + lane];
            float2 v2 = hp[(size_t)s2 * 64 + lane];
            float2 v3 = hp[(size_t)s3 * 64 + lane];
            a0.x += v0.x; a0.y += v0.y;
            a1.x += v1.x; a1.y += v1.y;
            a2.x += v2.x; a2.y += v2.y;
            a3.x += v3.x; a3.y += v3.y;
        }
        for (; i < e; i++) {
            float2 v = hp[(size_t)csr[i] * 64 + lane];
            a0.x += v.x; a0.y += v.y;
        }
        ((float2*)z)[(size_t)node * 64 + lane] =
            make_float2(a0.x + a1.x + a2.x + a3.x, a0.y + a1.y + a2.y + a3.y);
    } else {
        float a0 = h[(size_t)node * 64 + lane];
        float a1 = 0.f, a2 = 0.f, a3 = 0.f;
        int i = s;
        for (; i + 3 < e; i += 4) {
            a0 += h[(size_t)csr[i] * 64 + lane];
            a1 += h[(size_t)csr[i + 1] * 64 + lane];
            a2 += h[(size_t)csr[i + 2] * 64 + lane];
            a3 += h[(size_t)csr[i + 3] * 64 + lane];
        }
        for (; i < e; i++) a0 += h[(size_t)csr[i] * 64 + lane];
        z[(size_t)node * 64 + lane] = a0 + a1 + a2 + a3;
    }
}

// ---------------- merged weight reorder (all 6 matrices, one launch) ----------------
__global__ void reorder_all_kernel(const void* w0, const void* w1, const void* w2,
                                   const void* w3, const void* w4, const void* w5,
                                   unsigned short* __restrict__ wfbase,
                                   const int* __restrict__ flagp) {
    int b = blockIdx.x;
    int mat, boff;
    if (b < 32) { mat = 0; boff = b; }
    else { mat = 1 + (b - 32) / 64; boff = (b - 32) % 64; }
    const void* W = mat == 0 ? w0 : mat == 1 ? w1 : mat == 2 ? w2
                  : mat == 3 ? w3 : mat == 4 ? w4 : w5;
    int KC = (mat == 0) ? 2 : 4;
    int flag = *flagp;
    int idx = boff * 256 + threadIdx.x;
    int j  = idx & 7;
    int l  = (idx >> 3) & 63;
    int tc = idx >> 9;
    int c  = tc % KC;
    int t  = tc / KC;
    int k  = c * 32 + (l >> 4) * 8 + j;
    int n  = t * 16 + (l & 15);
    unsigned short v = flag ? f2b(((const float*)W)[k * 128 + n])
                            : ((const unsigned short*)W)[k * 128 + n];
    wfbase[mat * 16384 + idx] = v;
}

// ---------------- fused GIN MLP: Out = relu(relu(Z@W1+b1)@W2+b2) ----------------
// Block: 256 thr = 4 waves, 64 rows. mid tile staged in LDS as bf16 hi/lo,
// row stride 136 u16 (16B-aligned ds_read_b128, bank-incr 68%32=4 -> <=2-way).
// No barrier: each wave reads only the 16 rows it wrote.
template <int K1>
__global__ __launch_bounds__(256) void gin_mlp_kernel(
    const float* __restrict__ Z,
    const unsigned short* __restrict__ Wf1, const void* __restrict__ bias1,
    const unsigned short* __restrict__ Wf2, const void* __restrict__ bias2,
    float* __restrict__ Out, int M, const int* __restrict__ flagp) {
    constexpr int KC1 = K1 / 32;
    __shared__ unsigned short lds_hi[64 * 136];
    __shared__ unsigned short lds_lo[64 * 136];

    int flag = *flagp;
    int wave = threadIdx.x >> 6;
    int lane = threadIdx.x & 63;
    int m_ = lane & 15;
    int q  = lane >> 4;
    int rowbase = blockIdx.x * 64 + wave * 16;
    int row  = rowbase + m_;
    int rowc = row < M ? row : (M - 1);

    const float* zrow = Z + (size_t)rowc * K1 + q * 8;
    const unsigned short* wfl1 = Wf1 + lane * 8;
    const unsigned short* wfl2 = Wf2 + lane * 8;

    f32x4 acc[8];
#pragma unroll
    for (int t = 0; t < 8; t++) acc[t] = (f32x4)(0.0f);

    // ---- phase 1: mid = Z @ W1 (A from global fp32, split hi/lo) ----
#pragma unroll
    for (int c = 0; c < KC1; c++) {
        float4 h0 = *(const float4*)(zrow + c * 32);
        float4 h1 = *(const float4*)(zrow + c * 32 + 4);
        float vf[8] = {h0.x, h0.y, h0.z, h0.w, h1.x, h1.y, h1.z, h1.w};
        u16x8 hi_us, lo_us;
#pragma unroll
        for (int j = 0; j < 8; j++) {
            unsigned short hb = f2b(vf[j]);
            hi_us[j] = hb;
            lo_us[j] = f2b(vf[j] - b2f(hb));
        }
        bf16x8 ahi = __builtin_bit_cast(bf16x8, hi_us);
        bf16x8 alo = __builtin_bit_cast(bf16x8, lo_us);
#pragma unroll
        for (int t = 0; t < 8; t++) {
            bf16x8 b = *reinterpret_cast<const bf16x8*>(wfl1 + ((t * KC1 + c) << 9));
            acc[t] = __builtin_amdgcn_mfma_f32_16x16x32_bf16(ahi, b, acc[t], 0, 0, 0);
            acc[t] = __builtin_amdgcn_mfma_f32_16x16x32_bf16(alo, b, acc[t], 0, 0, 0);
        }
    }

    // ---- epilogue 1: +b1, relu, split -> LDS hi/lo ----
#pragma unroll
    for (int r = 0; r < 4; r++) {
        int lr = wave * 16 + q * 4 + r;   // local row
#pragma unroll
        for (int t = 0; t < 8; t++) {
            int col = t * 16 + m_;
            float bv = flag ? ((const float*)bias1)[col]
                            : b2f(((const unsigned short*)bias1)[col]);
            float v = acc[t][r] + bv;
            v = v > 0.0f ? v : 0.0f;
            unsigned short hb = f2b(v);
            lds_hi[lr * 136 + col] = hb;
            lds_lo[lr * 136 + col] = f2b(v - b2f(hb));
        }
    }

#pragma unroll
    for (int t = 0; t < 8; t++) acc[t] = (f32x4)(0.0f);

    // ---- phase 2: h = mid @ W2 (A from LDS, pre-split) ----
    int lr2 = wave * 16 + m_;
#pragma unroll
    for (int c = 0; c < 4; c++) {
        bf16x8 ahi = *reinterpret_cast<const bf16x8*>(&lds_hi[lr2 * 136 + c * 32 + q * 8]);
        bf16x8 alo = *reinterpret_cast<const bf16x8*>(&lds_lo[lr2 * 136 + c * 32 + q * 8]);
#pragma unroll
        for (int t = 0; t < 8; t++) {
            bf16x8 b = *reinterpret_cast<const bf16x8*>(wfl2 + ((t * 4 + c) << 9));
            acc[t] = __builtin_amdgcn_mfma_f32_16x16x32_bf16(ahi, b, acc[t], 0, 0, 0);
            acc[t] = __builtin_amdgcn_mfma_f32_16x16x32_bf16(alo, b, acc[t], 0, 0, 0);
        }
    }

    // ---- epilogue 2: +b2, relu, store ----
#pragma unroll
    for (int r = 0; r < 4; r++) {
        int orow = rowbase + q * 4 + r;
        if (orow < M) {
            float* op = Out + (size_t)orow * HID;
#pragma unroll
            for (int t = 0; t < 8; t++) {
                int col = t * 16 + m_;
                float bv = flag ? ((const float*)bias2)[col]
                                : b2f(((const unsigned short*)bias2)[col]);
                float v = acc[t][r] + bv;
                op[col] = v > 0.0f ? v : 0.0f;
            }
        }
    }
}

// ---------------- pooling: (graph, segment) 2D grid, atomic combine ----------------
#define POOL_SEG 8
__global__ __launch_bounds__(128) void pool_kernel(const float* __restrict__ h,
        const int* __restrict__ gstart, float* __restrict__ psum,
        unsigned int* __restrict__ pmax) {
    int g = blockIdx.x;
    int seg = blockIdx.y;
    int f = threadIdx.x;
    int s = gstart[g], e = gstart[g + 1];
    int len = e - s;
    if (len <= 0) return;
    int chunk = (len + POOL_SEG - 1) / POOL_SEG;
    int s2 = s + seg * chunk;
    int e2 = s2 + chunk < e ? s2 + chunk : e;
    if (s2 >= e2) return;
    float sum = 0.0f, mx = 0.0f;   // h >= 0 post-relu
    for (int i = s2; i < e2; i++) {
        float v = h[(size_t)i * HID + f];
        sum += v;
        mx = fmaxf(mx, v);
    }
    atomicAdd(&psum[g * HID + f], sum);
    atomicMax(&pmax[g * HID + f], __float_as_uint(mx));
}

// ---------------- head ----------------
__global__ __launch_bounds__(128) void head_kernel(
    const float* __restrict__ psum, const unsigned int* __restrict__ pmax,
    const int* __restrict__ gstart,
    const void* __restrict__ w1, const void* __restrict__ b1,
    const void* __restrict__ w2, const void* __restrict__ b2,
    void* __restrict__ out, const int* __restrict__ flagp) {
    int g = blockIdx.x;
    int n = threadIdx.x;
    int flag = *flagp;
    __shared__ float repr[2 * HID];
    __shared__ float red[HID];

    float c = (float)(gstart[g + 1] - gstart[g]);
    float inv = 1.0f / fmaxf(c, 1.0f);
    repr[n]       = psum[g * HID + n] * inv;
    repr[HID + n] = __uint_as_float(pmax[g * HID + n]);
    __syncthreads();

    float acc = flag ? ((const float*)b1)[n] : b2f(((const unsigned short*)b1)[n]);
    for (int k = 0; k < 2 * HID; k++) {
        float w = flag ? ((const float*)w1)[k * HID + n]
                       : b2f(((const unsigned short*)w1)[k * HID + n]);
        acc += repr[k] * w;
    }
    acc = fmaxf(acc, 0.0f);

    float w2v = flag ? ((const float*)w2)[n] : b2f(((const unsigned short*)w2)[n]);
    red[n] = acc * w2v;
    __syncthreads();
    for (int s = 64; s > 0; s >>= 1) {
        if (n < s) red[n] += red[n + s];
        __syncthreads();
    }
    if (n == 0) {
        float b2v = flag ? ((const float*)b2)[0] : b2f(((const unsigned short*)b2)[0]);
        float logit = red[0] + b2v;
        float sv = 1.0f / (1.0f + expf(-logit));
        if (flag) ((float*)out)[g] = sv;
        else      ((unsigned short*)out)[g] = f2b(sv);
    }
}

extern "C" void kernel_launch(void* const* d_in, const int* in_sizes, int n_in,
                              void* d_out, int out_size, void* d_ws, size_t ws_size,
                              hipStream_t stream) {
    const int* edge = (const int*)d_in[1];
    const int* srcv = edge;
    const int* dstv = edge + N_EDGES;
    const int* batch = (const int*)d_in[2];

    char* ws = (char*)d_ws;
    float* A = (float*)ws;                         // 25.6 MB
    float* B = (float*)(ws + 25600000);            // 25.6 MB
    int* off    = (int*)(ws + 51200000);
    int* cursor = (int*)(ws + 51400704);
    int* deg    = (int*)(ws + 51601408);
    int* csr    = (int*)(ws + 51802112);           // 3.2 MB
    unsigned short* wfbase = (unsigned short*)(ws + 55002112);  // 6 x 32 KB
    float* psum  = (float*)(ws + 55198720);        // 128 KB
    unsigned int* pmax = (unsigned int*)(ws + 55329792); // 128 KB
    int* partial = (int*)(ws + 55460864);
    int* pscan   = (int*)(ws + 55461888);
    int* gstart  = (int*)(ws + 55462912);
    int* flagp   = (int*)(ws + 55464960);

    const size_t NEED = 55500000;
    if (ws_size < NEED) {
        unsigned int k = 0;
        while ((((size_t)1) << (k + 1)) <= ws_size && k < 62) k++;
        diag_kernel<<<1, 256, 0, stream>>>((unsigned short*)d_out,
                                           (unsigned short)(0x4000 | (k & 63)));
        return;
    }

    detect_kernel<<<1, 256, 0, stream>>>((const unsigned short*)d_in[0], flagp);
    hipMemsetAsync(deg, 0, N_NODES * 4, stream);
    hipMemsetAsync(psum, 0, 131072, stream);
    hipMemsetAsync(pmax, 0, 131072, stream);

    reorder_all_kernel<<<352, 256, 0, stream>>>(d_in[3], d_in[5], d_in[7], d_in[9],
                                                d_in[11], d_in[13], wfbase, flagp);

    // CSR build (once, reused for all 3 layers)
    degree_kernel<<<3125, 256, 0, stream>>>(dstv, deg);
    const int NBLK = (N_NODES + 255) / 256;   // 196
    scan1_kernel<<<NBLK, 256, 0, stream>>>(deg, partial);
    scan2_kernel<<<1, 256, 0, stream>>>(partial, pscan, off, NBLK);
    scan3_kernel<<<NBLK, 256, 0, stream>>>(deg, pscan, off, cursor);
    fill_kernel<<<3125, 256, 0, stream>>>(srcv, dstv, cursor, csr);

    gbounds_kernel<<<NBLK, 256, 0, stream>>>(batch, gstart);

    cvt_x_kernel<<<12500, 256, 0, stream>>>(d_in[0], A, N_NODES * IN_DIM, flagp);

    const int GEMM_GRID = (N_NODES + 63) / 64;  // 782
    const int GATHER_GRID = (N_NODES + 3) / 4;  // 12500

    // layer 0: 64 -> 128 (A: h0 -> B: z0 -> A: h1)
    gather_kernel<64><<<GATHER_GRID, 256, 0, stream>>>(A, off, csr, B);
    gin_mlp_kernel<64><<<GEMM_GRID, 256, 0, stream>>>(B, wfbase + 0 * 16384, d_in[4],
                                                      wfbase + 1 * 16384, d_in[6],
                                                      A, N_NODES, flagp);
    // layers 1,2: 128 -> 128 (ping-pong A <-> B)
    for (int l = 1; l < 3; l++) {
        gather_kernel<128><<<GATHER_GRID, 256, 0, stream>>>(A, off, csr, B);
        gin_mlp_kernel<128><<<GEMM_GRID, 256, 0, stream>>>(B, wfbase + (2 * l) * 16384,
                                                           d_in[4 + 4 * l],
                                                           wfbase + (2 * l + 1) * 16384,
                                                           d_in[6 + 4 * l],
                                                           A, N_NODES, flagp);
    }

    // readout + head (h3 is in A)
    dim3 pgrid(NUM_GRAPHS, POOL_SEG);
    pool_kernel<<<pgrid, 128, 0, stream>>>(A, gstart, psum, pmax);
    head_kernel<<<NUM_GRAPHS, 128, 0, stream>>>(psum, pmax, gstart,
                                                d_in[15], d_in[16], d_in[17], d_in[18],
                                                d_out, flagp);
}

// Round 6
// 436.344 us; speedup vs baseline: 8.5769x; 1.1003x over previous
//
#include <hip/hip_runtime.h>
#include <hip/hip_bf16.h>

#define N_NODES   50000
#define N_EDGES   800000
#define IN_DIM    64
#define HID       128
#define NUM_GRAPHS 256

typedef __bf16 bf16x8 __attribute__((ext_vector_type(8)));
typedef unsigned short u16x8 __attribute__((ext_vector_type(8)));
typedef float f32x4 __attribute__((ext_vector_type(4)));

__device__ __forceinline__ float b2f(unsigned short u) {
    return __uint_as_float(((unsigned int)u) << 16);
}
__device__ __forceinline__ unsigned short f2b(float f) {
    unsigned int x = __float_as_uint(f);
    x = (x + 0x7fffu + ((x >> 16) & 1u)) >> 16;   // RNE
    return (unsigned short)x;
}

// ---- dtype probe (bf16 vs fp32 inputs) ----
__global__ void detect_kernel(const unsigned short* __restrict__ x, int* __restrict__ flag) {
    __shared__ int cnt;
    if (threadIdx.x == 0) cnt = 0;
    __syncthreads();
    int c = 0;
    for (int j = 0; j < 16; j++) {
        unsigned short u = x[2 * (threadIdx.x * 16 + j)];
        int e = (u >> 7) & 0xff;
        if (e <= 100 || e >= 140) c++;
    }
    atomicAdd(&cnt, c);
    __syncthreads();
    if (threadIdx.x == 0) *flag = (cnt > 1024) ? 1 : 0;   // 1 = fp32, 0 = bf16
}

__global__ void diag_kernel(unsigned short* out, unsigned short pat) {
    out[threadIdx.x] = pat;
}

// h0 (bf16) from x (either dtype)
__global__ void cvt_x_kernel(const void* __restrict__ x, unsigned short* __restrict__ h,
                             int n, const int* __restrict__ flagp) {
    int t = blockIdx.x * 256 + threadIdx.x;
    if (t >= n) return;
    int flag = *flagp;
    h[t] = flag ? f2b(((const float*)x)[t]) : ((const unsigned short*)x)[t];
}

// ---------------- CSR build (counting sort by dst) ----------------

__global__ void degree_kernel(const int* __restrict__ dst, int* __restrict__ deg) {
    int e = blockIdx.x * 256 + threadIdx.x;
    if (e < N_EDGES) atomicAdd(&deg[dst[e]], 1);
}

__global__ __launch_bounds__(256) void scan1_kernel(const int* __restrict__ deg,
                                                    int* __restrict__ partial) {
    __shared__ int s[256];
    int i = blockIdx.x * 256 + threadIdx.x;
    s[threadIdx.x] = (i < N_NODES) ? deg[i] : 0;
    __syncthreads();
    for (int d = 128; d > 0; d >>= 1) {
        if (threadIdx.x < d) s[threadIdx.x] += s[threadIdx.x + d];
        __syncthreads();
    }
    if (threadIdx.x == 0) partial[blockIdx.x] = s[0];
}

__global__ __launch_bounds__(256) void scan2_kernel(const int* __restrict__ partial,
                                                    int* __restrict__ pscan,
                                                    int* __restrict__ off, int nblk) {
    __shared__ int s[256];
    int tid = threadIdx.x;
    int v = (tid < nblk) ? partial[tid] : 0;
    s[tid] = v;
    __syncthreads();
    for (int d = 1; d < 256; d <<= 1) {
        int t = (tid >= d) ? s[tid - d] : 0;
        __syncthreads();
        s[tid] += t;
        __syncthreads();
    }
    if (tid < nblk) pscan[tid] = s[tid] - v;   // exclusive
    if (tid == 255) off[N_NODES] = s[255];     // total
}

__global__ __launch_bounds__(256) void scan3_kernel(const int* __restrict__ deg,
                                                    const int* __restrict__ pscan,
                                                    int* __restrict__ off,
                                                    int* __restrict__ cursor) {
    __shared__ int s[256];
    int i = blockIdx.x * 256 + threadIdx.x;
    int tid = threadIdx.x;
    int v = (i < N_NODES) ? deg[i] : 0;
    s[tid] = v;
    __syncthreads();
    for (int d = 1; d < 256; d <<= 1) {
        int t = (tid >= d) ? s[tid - d] : 0;
        __syncthreads();
        s[tid] += t;
        __syncthreads();
    }
    if (i < N_NODES) {
        int o = pscan[blockIdx.x] + s[tid] - v;
        off[i] = o;
        cursor[i] = o;
    }
}

__global__ void fill_kernel(const int* __restrict__ src, const int* __restrict__ dst,
                            int* __restrict__ cursor, int* __restrict__ csr) {
    int e = blockIdx.x * 256 + threadIdx.x;
    if (e >= N_EDGES) return;
    int p = atomicAdd(&cursor[dst[e]], 1);
    csr[p] = src[e];
}

// graph ranges (batch sorted) + zero-init pooling buffers (folds two memsets)
__global__ void gbounds_kernel(const int* __restrict__ batch, int* __restrict__ gstart,
                               float* __restrict__ psum, unsigned int* __restrict__ pmax) {
    int i = blockIdx.x * 256 + threadIdx.x;
    if (i < NUM_GRAPHS * HID) { psum[i] = 0.0f; pmax[i] = 0u; }
    if (i >= N_NODES) return;
    int b1 = batch[i];
    int b0 = (i == 0) ? -1 : batch[i - 1];
    for (int g = b0 + 1; g <= b1; g++) gstart[g] = i;
    if (i == N_NODES - 1)
        for (int g = b1 + 1; g <= NUM_GRAPHS; g++) gstart[g] = N_NODES;
}

// ---------------- gather: z[i] = h[i] + sum_{j->i} h[j]  (bf16 in/out, fp32 accum) ----------------
template <int DIM>
__global__ __launch_bounds__(256) void gather_kernel(const unsigned short* __restrict__ h,
        const int* __restrict__ off, const int* __restrict__ csr,
        unsigned short* __restrict__ z) {
    int node = blockIdx.x * 4 + (threadIdx.x >> 6);
    if (node >= N_NODES) return;
    int lane = threadIdx.x & 63;
    int s = off[node], e = off[node + 1];
    if constexpr (DIM == 128) {
        const ushort2* hp = (const ushort2*)h;
        ushort2 u = hp[(size_t)node * 64 + lane];
        float ax = b2f(u.x), ay = b2f(u.y);
        float bx = 0.f, by = 0.f, cx = 0.f, cy = 0.f, dx = 0.f, dy = 0.f;
        int i = s;
        for (; i + 3 < e; i += 4) {
            ushort2 v0 = hp[(size_t)csr[i] * 64 + lane];
            ushort2 v1 = hp[(size_t)csr[i + 1] * 64 + lane];
            ushort2 v2 = hp[(size_t)csr[i + 2] * 64 + lane];
            ushort2 v3 = hp[(size_t)csr[i + 3] * 64 + lane];
            ax += b2f(v0.x); ay += b2f(v0.y);
            bx += b2f(v1.x); by += b2f(v1.y);
            cx += b2f(v2.x); cy += b2f(v2.y);
            dx += b2f(v3.x); dy += b2f(v3.y);
        }
        for (; i < e; i++) {
            ushort2 v = hp[(size_t)csr[i] * 64 + lane];
            ax += b2f(v.x); ay += b2f(v.y);
        }
        ushort2 o; o.x = f2b(ax + bx + cx + dx); o.y = f2b(ay + by + cy + dy);
        ((ushort2*)z)[(size_t)node * 64 + lane] = o;
    } else {
        float a0 = b2f(h[(size_t)node * 64 + lane]);
        float a1 = 0.f, a2 = 0.f, a3 = 0.f;
        int i = s;
        for (; i + 3 < e; i += 4) {
            a0 += b2f(h[(size_t)csr[i] * 64 + lane]);
            a1 += b2f(h[(size_t)csr[i + 1] * 64 + lane]);
            a2 += b2f(h[(size_t)csr[i + 2] * 64 + lane]);
            a3 += b2f(h[(size_t)csr[i + 3] * 64 + lane]);
        }
        for (; i < e; i++) a0 += b2f(h[(size_t)csr[i] * 64 + lane]);
        z[(size_t)node * 64 + lane] = f2b(a0 + a1 + a2 + a3);
    }
}

// ---------------- merged weight reorder (all 6 matrices, one launch) ----------------
__global__ void reorder_all_kernel(const void* w0, const void* w1, const void* w2,
                                   const void* w3, const void* w4, const void* w5,
                                   unsigned short* __restrict__ wfbase,
                                   const int* __restrict__ flagp) {
    int b = blockIdx.x;
    int mat, boff;
    if (b < 32) { mat = 0; boff = b; }
    else { mat = 1 + (b - 32) / 64; boff = (b - 32) % 64; }
    const void* W = mat == 0 ? w0 : mat == 1 ? w1 : mat == 2 ? w2
                  : mat == 3 ? w3 : mat == 4 ? w4 : w5;
    int KC = (mat == 0) ? 2 : 4;
    int flag = *flagp;
    int idx = boff * 256 + threadIdx.x;
    int j  = idx & 7;
    int l  = (idx >> 3) & 63;
    int tc = idx >> 9;
    int c  = tc % KC;
    int t  = tc / KC;
    int k  = c * 32 + (l >> 4) * 8 + j;
    int n  = t * 16 + (l & 15);
    unsigned short v = flag ? f2b(((const float*)W)[k * 128 + n])
                            : ((const unsigned short*)W)[k * 128 + n];
    wfbase[mat * 16384 + idx] = v;
}

// ---------------- fused GIN MLP: Out = relu(relu(Z@W1+b1)@W2+b2) ----------------
// Z is bf16 (exact MFMA A operand -> single MFMA in phase 1). mid stays ~fp32
// via LDS hi/lo split for phase 2. Out written bf16. No barrier needed: each
// wave consumes exactly the 16 LDS rows it produced.
template <int K1>
__global__ __launch_bounds__(256) void gin_mlp_kernel(
    const unsigned short* __restrict__ Z,
    const unsigned short* __restrict__ Wf1, const void* __restrict__ bias1,
    const unsigned short* __restrict__ Wf2, const void* __restrict__ bias2,
    unsigned short* __restrict__ Out, int M, const int* __restrict__ flagp) {
    constexpr int KC1 = K1 / 32;
    __shared__ unsigned short lds_hi[64 * 136];
    __shared__ unsigned short lds_lo[64 * 136];

    int flag = *flagp;
    int wave = threadIdx.x >> 6;
    int lane = threadIdx.x & 63;
    int m_ = lane & 15;
    int q  = lane >> 4;
    int rowbase = blockIdx.x * 64 + wave * 16;
    int row  = rowbase + m_;
    int rowc = row < M ? row : (M - 1);

    const unsigned short* zrow = Z + (size_t)rowc * K1 + q * 8;
    const unsigned short* wfl1 = Wf1 + lane * 8;
    const unsigned short* wfl2 = Wf2 + lane * 8;

    f32x4 acc[8];
#pragma unroll
    for (int t = 0; t < 8; t++) acc[t] = (f32x4)(0.0f);

    // ---- phase 1: mid = Z @ W1 (A = bf16 direct) ----
#pragma unroll
    for (int c = 0; c < KC1; c++) {
        bf16x8 a = *reinterpret_cast<const bf16x8*>(zrow + c * 32);
#pragma unroll
        for (int t = 0; t < 8; t++) {
            bf16x8 b = *reinterpret_cast<const bf16x8*>(wfl1 + ((t * KC1 + c) << 9));
            acc[t] = __builtin_amdgcn_mfma_f32_16x16x32_bf16(a, b, acc[t], 0, 0, 0);
        }
    }

    // ---- epilogue 1: +b1, relu, hi/lo split -> LDS ----
#pragma unroll
    for (int r = 0; r < 4; r++) {
        int lr = wave * 16 + q * 4 + r;   // local row
#pragma unroll
        for (int t = 0; t < 8; t++) {
            int col = t * 16 + m_;
            float bv = flag ? ((const float*)bias1)[col]
                            : b2f(((const unsigned short*)bias1)[col]);
            float v = acc[t][r] + bv;
            v = v > 0.0f ? v : 0.0f;
            unsigned short hb = f2b(v);
            lds_hi[lr * 136 + col] = hb;
            lds_lo[lr * 136 + col] = f2b(v - b2f(hb));
        }
    }

#pragma unroll
    for (int t = 0; t < 8; t++) acc[t] = (f32x4)(0.0f);

    // ---- phase 2: h = mid @ W2 (A from LDS, pre-split) ----
    int lr2 = wave * 16 + m_;
#pragma unroll
    for (int c = 0; c < 4; c++) {
        bf16x8 ahi = *reinterpret_cast<const bf16x8*>(&lds_hi[lr2 * 136 + c * 32 + q * 8]);
        bf16x8 alo = *reinterpret_cast<const bf16x8*>(&lds_lo[lr2 * 136 + c * 32 + q * 8]);
#pragma unroll
        for (int t = 0; t < 8; t++) {
            bf16x8 b = *reinterpret_cast<const bf16x8*>(wfl2 + ((t * 4 + c) << 9));
            acc[t] = __builtin_amdgcn_mfma_f32_16x16x32_bf16(ahi, b, acc[t], 0, 0, 0);
            acc[t] = __builtin_amdgcn_mfma_f32_16x16x32_bf16(alo, b, acc[t], 0, 0, 0);
        }
    }

    // ---- epilogue 2: +b2, relu, store bf16 ----
#pragma unroll
    for (int r = 0; r < 4; r++) {
        int orow = rowbase + q * 4 + r;
        if (orow < M) {
            unsigned short* op = Out + (size_t)orow * HID;
#pragma unroll
            for (int t = 0; t < 8; t++) {
                int col = t * 16 + m_;
                float bv = flag ? ((const float*)bias2)[col]
                                : b2f(((const unsigned short*)bias2)[col]);
                float v = acc[t][r] + bv;
                op[col] = f2b(v > 0.0f ? v : 0.0f);
            }
        }
    }
}

// ---------------- pooling: (graph, segment) 2D grid, atomic combine ----------------
#define POOL_SEG 8
__global__ __launch_bounds__(128) void pool_kernel(const unsigned short* __restrict__ h,
        const int* __restrict__ gstart, float* __restrict__ psum,
        unsigned int* __restrict__ pmax) {
    int g = blockIdx.x;
    int seg = blockIdx.y;
    int f = threadIdx.x;
    int s = gstart[g], e = gstart[g + 1];
    int len = e - s;
    if (len <= 0) return;
    int chunk = (len + POOL_SEG - 1) / POOL_SEG;
    int s2 = s + seg * chunk;
    int e2 = s2 + chunk < e ? s2 + chunk : e;
    if (s2 >= e2) return;
    float sum = 0.0f, mx = 0.0f;   // h >= 0 post-relu
    for (int i = s2; i < e2; i++) {
        float v = b2f(h[(size_t)i * HID + f]);
        sum += v;
        mx = fmaxf(mx, v);
    }
    atomicAdd(&psum[g * HID + f], sum);
    atomicMax(&pmax[g * HID + f], __float_as_uint(mx));
}

// ---------------- head ----------------
__global__ __launch_bounds__(128) void head_kernel(
    const float* __restrict__ psum, const unsigned int* __restrict__ pmax,
    const int* __restrict__ gstart,
    const void* __restrict__ w1, const void* __restrict__ b1,
    const void* __restrict__ w2, const void* __restrict__ b2,
    void* __restrict__ out, const int* __restrict__ flagp) {
    int g = blockIdx.x;
    int n = threadIdx.x;
    int flag = *flagp;
    __shared__ float repr[2 * HID];
    __shared__ float red[HID];

    float c = (float)(gstart[g + 1] - gstart[g]);
    float inv = 1.0f / fmaxf(c, 1.0f);
    repr[n]       = psum[g * HID + n] * inv;
    repr[HID + n] = __uint_as_float(pmax[g * HID + n]);
    __syncthreads();

    float acc = flag ? ((const float*)b1)[n] : b2f(((const unsigned short*)b1)[n]);
    for (int k = 0; k < 2 * HID; k++) {
        float w = flag ? ((const float*)w1)[k * HID + n]
                       : b2f(((const unsigned short*)w1)[k * HID + n]);
        acc += repr[k] * w;
    }
    acc = fmaxf(acc, 0.0f);

    float w2v = flag ? ((const float*)w2)[n] : b2f(((const unsigned short*)w2)[n]);
    red[n] = acc * w2v;
    __syncthreads();
    for (int s = 64; s > 0; s >>= 1) {
        if (n < s) red[n] += red[n + s];
        __syncthreads();
    }
    if (n == 0) {
        float b2v = flag ? ((const float*)b2)[0] : b2f(((const unsigned short*)b2)[0]);
        float logit = red[0] + b2v;
        float sv = 1.0f / (1.0f + expf(-logit));
        if (flag) ((float*)out)[g] = sv;
        else      ((unsigned short*)out)[g] = f2b(sv);
    }
}

extern "C" void kernel_launch(void* const* d_in, const int* in_sizes, int n_in,
                              void* d_out, int out_size, void* d_ws, size_t ws_size,
                              hipStream_t stream) {
    const int* edge = (const int*)d_in[1];
    const int* srcv = edge;
    const int* dstv = edge + N_EDGES;
    const int* batch = (const int*)d_in[2];

    char* ws = (char*)d_ws;
    unsigned short* A = (unsigned short*)ws;              // 12.8 MB (bf16 h)
    unsigned short* B = (unsigned short*)(ws + 25600000); // 12.8 MB (bf16 z)
    int* off    = (int*)(ws + 51200000);
    int* cursor = (int*)(ws + 51400704);
    int* deg    = (int*)(ws + 51601408);
    int* csr    = (int*)(ws + 51802112);           // 3.2 MB
    unsigned short* wfbase = (unsigned short*)(ws + 55002112);  // 6 x 32 KB
    float* psum  = (float*)(ws + 55198720);        // 128 KB
    unsigned int* pmax = (unsigned int*)(ws + 55329792); // 128 KB
    int* partial = (int*)(ws + 55460864);
    int* pscan   = (int*)(ws + 55461888);
    int* gstart  = (int*)(ws + 55462912);
    int* flagp   = (int*)(ws + 55464960);

    const size_t NEED = 55500000;
    if (ws_size < NEED) {
        unsigned int k = 0;
        while ((((size_t)1) << (k + 1)) <= ws_size && k < 62) k++;
        diag_kernel<<<1, 256, 0, stream>>>((unsigned short*)d_out,
                                           (unsigned short)(0x4000 | (k & 63)));
        return;
    }

    detect_kernel<<<1, 256, 0, stream>>>((const unsigned short*)d_in[0], flagp);
    hipMemsetAsync(deg, 0, N_NODES * 4, stream);

    reorder_all_kernel<<<352, 256, 0, stream>>>(d_in[3], d_in[5], d_in[7], d_in[9],
                                                d_in[11], d_in[13], wfbase, flagp);

    // CSR build (once, reused for all 3 layers)
    degree_kernel<<<3125, 256, 0, stream>>>(dstv, deg);
    const int NBLK = (N_NODES + 255) / 256;   // 196
    scan1_kernel<<<NBLK, 256, 0, stream>>>(deg, partial);
    scan2_kernel<<<1, 256, 0, stream>>>(partial, pscan, off, NBLK);
    scan3_kernel<<<NBLK, 256, 0, stream>>>(deg, pscan, off, cursor);
    fill_kernel<<<3125, 256, 0, stream>>>(srcv, dstv, cursor, csr);

    gbounds_kernel<<<NBLK, 256, 0, stream>>>(batch, gstart, psum, pmax);

    cvt_x_kernel<<<12500, 256, 0, stream>>>(d_in[0], A, N_NODES * IN_DIM, flagp);

    const int GEMM_GRID = (N_NODES + 63) / 64;  // 782
    const int GATHER_GRID = (N_NODES + 3) / 4;  // 12500

    // layer 0: 64 -> 128 (A: h0 -> B: z0 -> A: h1)
    gather_kernel<64><<<GATHER_GRID, 256, 0, stream>>>(A, off, csr, B);
    gin_mlp_kernel<64><<<GEMM_GRID, 256, 0, stream>>>(B, wfbase + 0 * 16384, d_in[4],
                                                      wfbase + 1 * 16384, d_in[6],
                                                      A, N_NODES, flagp);
    // layers 1,2: 128 -> 128 (A -> B -> A)
    for (int l = 1; l < 3; l++) {
        gather_kernel<128><<<GATHER_GRID, 256, 0, stream>>>(A, off, csr, B);
        gin_mlp_kernel<128><<<GEMM_GRID, 256, 0, stream>>>(B, wfbase + (2 * l) * 16384,
                                                           d_in[4 + 4 * l],
                                                           wfbase + (2 * l + 1) * 16384,
                                                           d_in[6 + 4 * l],
                                                           A, N_NODES, flagp);
    }

    // readout + head (h3 in A)
    dim3 pgrid(NUM_GRAPHS, POOL_SEG);
    pool_kernel<<<pgrid, 128, 0, stream>>>(A, gstart, psum, pmax);
    head_kernel<<<NUM_GRAPHS, 128, 0, stream>>>(psum, pmax, gstart,
                                                d_in[15], d_in[16], d_in[17], d_in[18],
                                                d_out, flagp);
}

// Round 7
// 371.895 us; speedup vs baseline: 10.0632x; 1.1733x over previous
//
#include <hip/hip_runtime.h>
#include <hip/hip_bf16.h>

#define N_NODES   50000
#define N_EDGES   800000
#define IN_DIM    64
#define HID       128
#define NUM_GRAPHS 256
#define NBUCK     196   // ceil(50000/256) buckets of 256 nodes

typedef __bf16 bf16x8 __attribute__((ext_vector_type(8)));
typedef unsigned short u16x8 __attribute__((ext_vector_type(8)));
typedef float f32x4 __attribute__((ext_vector_type(4)));

__device__ __forceinline__ float b2f(unsigned short u) {
    return __uint_as_float(((unsigned int)u) << 16);
}
__device__ __forceinline__ unsigned short f2b(float f) {
    unsigned int x = __float_as_uint(f);
    x = (x + 0x7fffu + ((x >> 16) & 1u)) >> 16;   // RNE
    return (unsigned short)x;
}

// ---- dtype probe (bf16 vs fp32 inputs) + zero bucket counters ----
__global__ void detect_kernel(const unsigned short* __restrict__ x, int* __restrict__ flag,
                              int* __restrict__ bcnt) {
    if (threadIdx.x < NBUCK) bcnt[threadIdx.x] = 0;
    __shared__ int cnt;
    if (threadIdx.x == 0) cnt = 0;
    __syncthreads();
    int c = 0;
    for (int j = 0; j < 16; j++) {
        unsigned short u = x[2 * (threadIdx.x * 16 + j)];
        int e = (u >> 7) & 0xff;
        if (e <= 100 || e >= 140) c++;
    }
    atomicAdd(&cnt, c);
    __syncthreads();
    if (threadIdx.x == 0) *flag = (cnt > 1024) ? 1 : 0;   // 1 = fp32, 0 = bf16
}

__global__ void diag_kernel(unsigned short* out, unsigned short pat) {
    out[threadIdx.x] = pat;
}

// h0 (bf16) from x (either dtype)
__global__ void cvt_x_kernel(const void* __restrict__ x, unsigned short* __restrict__ h,
                             int n, const int* __restrict__ flagp) {
    int t = blockIdx.x * 256 + threadIdx.x;
    if (t >= n) return;
    int flag = *flagp;
    h[t] = flag ? f2b(((const float*)x)[t]) : ((const unsigned short*)x)[t];
}

// ---------------- bucketed CSR build ----------------
// bucket b = dst >> 8 covers nodes [256b, 256b+256)

// pass 1: per-bucket edge counts (LDS-aggregated)
__global__ __launch_bounds__(1024) void bcount_kernel(const int* __restrict__ dst,
                                                      int* __restrict__ bcnt) {
    __shared__ int l[NBUCK];
    int tid = threadIdx.x;
    if (tid < NBUCK) l[tid] = 0;
    __syncthreads();
    int e0 = blockIdx.x * 4096;
#pragma unroll
    for (int k = 0; k < 4; k++) {
        int e = e0 + k * 1024 + tid;
        if (e < N_EDGES) atomicAdd(&l[dst[e] >> 8], 1);
    }
    __syncthreads();
    if (tid < NBUCK && l[tid]) atomicAdd(&bcnt[tid], l[tid]);
}

// pass 2: scan bucket counts -> bbase, bcursor
__global__ __launch_bounds__(256) void bscan_kernel(const int* __restrict__ bcnt,
                                                    int* __restrict__ bbase,
                                                    int* __restrict__ bcursor) {
    __shared__ int sc[256];
    int tid = threadIdx.x;
    int v = (tid < NBUCK) ? bcnt[tid] : 0;
    sc[tid] = v;
    __syncthreads();
    for (int d = 1; d < 256; d <<= 1) {
        int t = (tid >= d) ? sc[tid - d] : 0;
        __syncthreads();
        sc[tid] += t;
        __syncthreads();
    }
    if (tid < NBUCK) { int b = sc[tid] - v; bbase[tid] = b; bcursor[tid] = b; }
    if (tid == 255) bbase[NBUCK] = sc[255];
}

// pass 3: scatter packed (dstLow<<16 | src) into bucket-contiguous ebuf.
// Block-aggregated allocation -> one global atomic per (block,bucket); writes
// land in ~84B consecutive chunks per bucket.
__global__ __launch_bounds__(1024) void bscatter_kernel(const int* __restrict__ src,
        const int* __restrict__ dst, int* __restrict__ bcursor,
        unsigned int* __restrict__ ebuf) {
    __shared__ int lcnt[NBUCK];
    __shared__ int lbase[NBUCK];
    __shared__ int lcur[NBUCK];
    int tid = threadIdx.x;
    if (tid < NBUCK) lcnt[tid] = 0;
    __syncthreads();
    int e0 = blockIdx.x * 4096;
    int d[4], s[4];
#pragma unroll
    for (int k = 0; k < 4; k++) {
        int e = e0 + k * 1024 + tid;
        if (e < N_EDGES) {
            d[k] = dst[e]; s[k] = src[e];
            atomicAdd(&lcnt[d[k] >> 8], 1);
        } else d[k] = -1;
    }
    __syncthreads();
    if (tid < NBUCK) {
        int c = lcnt[tid];
        lbase[tid] = c ? atomicAdd(&bcursor[tid], c) : 0;
        lcur[tid] = 0;
    }
    __syncthreads();
#pragma unroll
    for (int k = 0; k < 4; k++) {
        if (d[k] >= 0) {
            int b = d[k] >> 8;
            int p = lbase[b] + atomicAdd(&lcur[b], 1);
            ebuf[p] = ((unsigned int)(d[k] & 255) << 16) | (unsigned int)s[k];
        }
    }
}

// pass 4: per-bucket counting sort -> off (coalesced) + csr (ushort, hot 8KB window)
__global__ __launch_bounds__(256) void bsort_kernel(const unsigned int* __restrict__ ebuf,
        const int* __restrict__ bbase, int* __restrict__ off,
        unsigned short* __restrict__ csr) {
    __shared__ int lcnt[256];
    __shared__ int sc[256];
    __shared__ int lcur[256];
    int b = blockIdx.x, tid = threadIdx.x;
    int base = bbase[b], end = bbase[b + 1];
    int cnt = end - base;
    lcnt[tid] = 0;
    __syncthreads();
    for (int i = tid; i < cnt; i += 256)
        atomicAdd(&lcnt[ebuf[base + i] >> 16], 1);
    __syncthreads();
    int v = lcnt[tid];
    sc[tid] = v;
    __syncthreads();
    for (int d = 1; d < 256; d <<= 1) {
        int t = (tid >= d) ? sc[tid - d] : 0;
        __syncthreads();
        sc[tid] += t;
        __syncthreads();
    }
    int excl = sc[tid] - v;
    lcur[tid] = excl;
    int node = b * 256 + tid;
    if (node < N_NODES) off[node] = base + excl;
    if (b == 0 && tid == 0) off[N_NODES] = N_EDGES;
    __syncthreads();
    for (int i = tid; i < cnt; i += 256) {
        unsigned int ev = ebuf[base + i];
        int p = atomicAdd(&lcur[ev >> 16], 1);
        csr[base + p] = (unsigned short)(ev & 0xffffu);
    }
}

// graph ranges (batch sorted) + zero-init pooling buffers
__global__ void gbounds_kernel(const int* __restrict__ batch, int* __restrict__ gstart,
                               float* __restrict__ psum, unsigned int* __restrict__ pmax) {
    int i = blockIdx.x * 256 + threadIdx.x;
    if (i < NUM_GRAPHS * HID) { psum[i] = 0.0f; pmax[i] = 0u; }
    if (i >= N_NODES) return;
    int b1 = batch[i];
    int b0 = (i == 0) ? -1 : batch[i - 1];
    for (int g = b0 + 1; g <= b1; g++) gstart[g] = i;
    if (i == N_NODES - 1)
        for (int g = b1 + 1; g <= NUM_GRAPHS; g++) gstart[g] = N_NODES;
}

// ---------------- gather: z[i] = h[i] + sum_{j->i} h[j]  (bf16 in/out, fp32 accum) ----------------
template <int DIM>
__global__ __launch_bounds__(256) void gather_kernel(const unsigned short* __restrict__ h,
        const int* __restrict__ off, const unsigned short* __restrict__ csr,
        unsigned short* __restrict__ z) {
    int node = blockIdx.x * 4 + (threadIdx.x >> 6);
    if (node >= N_NODES) return;
    int lane = threadIdx.x & 63;
    int s = off[node], e = off[node + 1];
    if constexpr (DIM == 128) {
        const ushort2* hp = (const ushort2*)h;
        ushort2 u = hp[(size_t)node * 64 + lane];
        float ax = b2f(u.x), ay = b2f(u.y);
        float bx = 0.f, by = 0.f, cx = 0.f, cy = 0.f, dx = 0.f, dy = 0.f;
        int i = s;
        for (; i + 3 < e; i += 4) {
            ushort2 v0 = hp[(size_t)csr[i] * 64 + lane];
            ushort2 v1 = hp[(size_t)csr[i + 1] * 64 + lane];
            ushort2 v2 = hp[(size_t)csr[i + 2] * 64 + lane];
            ushort2 v3 = hp[(size_t)csr[i + 3] * 64 + lane];
            ax += b2f(v0.x); ay += b2f(v0.y);
            bx += b2f(v1.x); by += b2f(v1.y);
            cx += b2f(v2.x); cy += b2f(v2.y);
            dx += b2f(v3.x); dy += b2f(v3.y);
        }
        for (; i < e; i++) {
            ushort2 v = hp[(size_t)csr[i] * 64 + lane];
            ax += b2f(v.x); ay += b2f(v.y);
        }
        ushort2 o; o.x = f2b(ax + bx + cx + dx); o.y = f2b(ay + by + cy + dy);
        ((ushort2*)z)[(size_t)node * 64 + lane] = o;
    } else {
        float a0 = b2f(h[(size_t)node * 64 + lane]);
        float a1 = 0.f, a2 = 0.f, a3 = 0.f;
        int i = s;
        for (; i + 3 < e; i += 4) {
            a0 += b2f(h[(size_t)csr[i] * 64 + lane]);
            a1 += b2f(h[(size_t)csr[i + 1] * 64 + lane]);
            a2 += b2f(h[(size_t)csr[i + 2] * 64 + lane]);
            a3 += b2f(h[(size_t)csr[i + 3] * 64 + lane]);
        }
        for (; i < e; i++) a0 += b2f(h[(size_t)csr[i] * 64 + lane]);
        z[(size_t)node * 64 + lane] = f2b(a0 + a1 + a2 + a3);
    }
}

// ---------------- merged weight reorder (all 6 matrices, one launch) ----------------
__global__ void reorder_all_kernel(const void* w0, const void* w1, const void* w2,
                                   const void* w3, const void* w4, const void* w5,
                                   unsigned short* __restrict__ wfbase,
                                   const int* __restrict__ flagp) {
    int b = blockIdx.x;
    int mat, boff;
    if (b < 32) { mat = 0; boff = b; }
    else { mat = 1 + (b - 32) / 64; boff = (b - 32) % 64; }
    const void* W = mat == 0 ? w0 : mat == 1 ? w1 : mat == 2 ? w2
                  : mat == 3 ? w3 : mat == 4 ? w4 : w5;
    int KC = (mat == 0) ? 2 : 4;
    int flag = *flagp;
    int idx = boff * 256 + threadIdx.x;
    int j  = idx & 7;
    int l  = (idx >> 3) & 63;
    int tc = idx >> 9;
    int c  = tc % KC;
    int t  = tc / KC;
    int k  = c * 32 + (l >> 4) * 8 + j;
    int n  = t * 16 + (l & 15);
    unsigned short v = flag ? f2b(((const float*)W)[k * 128 + n])
                            : ((const unsigned short*)W)[k * 128 + n];
    wfbase[mat * 16384 + idx] = v;
}

// ---------------- fused GIN MLP: Out = relu(relu(Z@W1+b1)@W2+b2) ----------------
template <int K1>
__global__ __launch_bounds__(256) void gin_mlp_kernel(
    const unsigned short* __restrict__ Z,
    const unsigned short* __restrict__ Wf1, const void* __restrict__ bias1,
    const unsigned short* __restrict__ Wf2, const void* __restrict__ bias2,
    unsigned short* __restrict__ Out, int M, const int* __restrict__ flagp) {
    constexpr int KC1 = K1 / 32;
    __shared__ unsigned short lds_hi[64 * 136];
    __shared__ unsigned short lds_lo[64 * 136];

    int flag = *flagp;
    int wave = threadIdx.x >> 6;
    int lane = threadIdx.x & 63;
    int m_ = lane & 15;
    int q  = lane >> 4;
    int rowbase = blockIdx.x * 64 + wave * 16;
    int row  = rowbase + m_;
    int rowc = row < M ? row : (M - 1);

    const unsigned short* zrow = Z + (size_t)rowc * K1 + q * 8;
    const unsigned short* wfl1 = Wf1 + lane * 8;
    const unsigned short* wfl2 = Wf2 + lane * 8;

    f32x4 acc[8];
#pragma unroll
    for (int t = 0; t < 8; t++) acc[t] = (f32x4)(0.0f);

    // phase 1: mid = Z @ W1 (A = bf16 direct)
#pragma unroll
    for (int c = 0; c < KC1; c++) {
        bf16x8 a = *reinterpret_cast<const bf16x8*>(zrow + c * 32);
#pragma unroll
        for (int t = 0; t < 8; t++) {
            bf16x8 b = *reinterpret_cast<const bf16x8*>(wfl1 + ((t * KC1 + c) << 9));
            acc[t] = __builtin_amdgcn_mfma_f32_16x16x32_bf16(a, b, acc[t], 0, 0, 0);
        }
    }

    // epilogue 1: +b1, relu, hi/lo split -> LDS
#pragma unroll
    for (int r = 0; r < 4; r++) {
        int lr = wave * 16 + q * 4 + r;
#pragma unroll
        for (int t = 0; t < 8; t++) {
            int col = t * 16 + m_;
            float bv = flag ? ((const float*)bias1)[col]
                            : b2f(((const unsigned short*)bias1)[col]);
            float v = acc[t][r] + bv;
            v = v > 0.0f ? v : 0.0f;
            unsigned short hb = f2b(v);
            lds_hi[lr * 136 + col] = hb;
            lds_lo[lr * 136 + col] = f2b(v - b2f(hb));
        }
    }

#pragma unroll
    for (int t = 0; t < 8; t++) acc[t] = (f32x4)(0.0f);

    // phase 2: h = mid @ W2 (A from LDS, pre-split)
    int lr2 = wave * 16 + m_;
#pragma unroll
    for (int c = 0; c < 4; c++) {
        bf16x8 ahi = *reinterpret_cast<const bf16x8*>(&lds_hi[lr2 * 136 + c * 32 + q * 8]);
        bf16x8 alo = *reinterpret_cast<const bf16x8*>(&lds_lo[lr2 * 136 + c * 32 + q * 8]);
#pragma unroll
        for (int t = 0; t < 8; t++) {
            bf16x8 b = *reinterpret_cast<const bf16x8*>(wfl2 + ((t * 4 + c) << 9));
            acc[t] = __builtin_amdgcn_mfma_f32_16x16x32_bf16(ahi, b, acc[t], 0, 0, 0);
            acc[t] = __builtin_amdgcn_mfma_f32_16x16x32_bf16(alo, b, acc[t], 0, 0, 0);
        }
    }

    // epilogue 2: +b2, relu, store bf16
#pragma unroll
    for (int r = 0; r < 4; r++) {
        int orow = rowbase + q * 4 + r;
        if (orow < M) {
            unsigned short* op = Out + (size_t)orow * HID;
#pragma unroll
            for (int t = 0; t < 8; t++) {
                int col = t * 16 + m_;
                float bv = flag ? ((const float*)bias2)[col]
                                : b2f(((const unsigned short*)bias2)[col]);
                float v = acc[t][r] + bv;
                op[col] = f2b(v > 0.0f ? v : 0.0f);
            }
        }
    }
}

// ---------------- pooling: (graph, segment) 2D grid, atomic combine ----------------
#define POOL_SEG 8
__global__ __launch_bounds__(128) void pool_kernel(const unsigned short* __restrict__ h,
        const int* __restrict__ gstart, float* __restrict__ psum,
        unsigned int* __restrict__ pmax) {
    int g = blockIdx.x;
    int seg = blockIdx.y;
    int f = threadIdx.x;
    int s = gstart[g], e = gstart[g + 1];
    int len = e - s;
    if (len <= 0) return;
    int chunk = (len + POOL_SEG - 1) / POOL_SEG;
    int s2 = s + seg * chunk;
    int e2 = s2 + chunk < e ? s2 + chunk : e;
    if (s2 >= e2) return;
    float sum = 0.0f, mx = 0.0f;   // h >= 0 post-relu
    for (int i = s2; i < e2; i++) {
        float v = b2f(h[(size_t)i * HID + f]);
        sum += v;
        mx = fmaxf(mx, v);
    }
    atomicAdd(&psum[g * HID + f], sum);
    atomicMax(&pmax[g * HID + f], __float_as_uint(mx));
}

// ---------------- head ----------------
__global__ __launch_bounds__(128) void head_kernel(
    const float* __restrict__ psum, const unsigned int* __restrict__ pmax,
    const int* __restrict__ gstart,
    const void* __restrict__ w1, const void* __restrict__ b1,
    const void* __restrict__ w2, const void* __restrict__ b2,
    void* __restrict__ out, const int* __restrict__ flagp) {
    int g = blockIdx.x;
    int n = threadIdx.x;
    int flag = *flagp;
    __shared__ float repr[2 * HID];
    __shared__ float red[HID];

    float c = (float)(gstart[g + 1] - gstart[g]);
    float inv = 1.0f / fmaxf(c, 1.0f);
    repr[n]       = psum[g * HID + n] * inv;
    repr[HID + n] = __uint_as_float(pmax[g * HID + n]);
    __syncthreads();

    float acc = flag ? ((const float*)b1)[n] : b2f(((const unsigned short*)b1)[n]);
    for (int k = 0; k < 2 * HID; k++) {
        float w = flag ? ((const float*)w1)[k * HID + n]
                       : b2f(((const unsigned short*)w1)[k * HID + n]);
        acc += repr[k] * w;
    }
    acc = fmaxf(acc, 0.0f);

    float w2v = flag ? ((const float*)w2)[n] : b2f(((const unsigned short*)w2)[n]);
    red[n] = acc * w2v;
    __syncthreads();
    for (int s = 64; s > 0; s >>= 1) {
        if (n < s) red[n] += red[n + s];
        __syncthreads();
    }
    if (n == 0) {
        float b2v = flag ? ((const float*)b2)[0] : b2f(((const unsigned short*)b2)[0]);
        float logit = red[0] + b2v;
        float sv = 1.0f / (1.0f + expf(-logit));
        if (flag) ((float*)out)[g] = sv;
        else      ((unsigned short*)out)[g] = f2b(sv);
    }
}

extern "C" void kernel_launch(void* const* d_in, const int* in_sizes, int n_in,
                              void* d_out, int out_size, void* d_ws, size_t ws_size,
                              hipStream_t stream) {
    const int* edge = (const int*)d_in[1];
    const int* srcv = edge;
    const int* dstv = edge + N_EDGES;
    const int* batch = (const int*)d_in[2];

    char* ws = (char*)d_ws;
    unsigned short* A = (unsigned short*)ws;               // 12.8 MB (bf16 h)
    unsigned short* B = (unsigned short*)(ws + 12800000);  // 12.8 MB (bf16 z)
    unsigned int* ebuf = (unsigned int*)(ws + 25600000);   // 3.2 MB packed edges
    unsigned short* csr = (unsigned short*)(ws + 28800000);// 1.6 MB
    int* off    = (int*)(ws + 30400000);                   // 50001 ints
    unsigned short* wfbase = (unsigned short*)(ws + 30604800);  // 6 x 32 KB
    float* psum  = (float*)(ws + 30801408);                // 128 KB
    unsigned int* pmax = (unsigned int*)(ws + 30932480);   // 128 KB
    int* bcnt    = (int*)(ws + 31063552);
    int* bbase   = (int*)(ws + 31064576);
    int* bcursor = (int*)(ws + 31065600);
    int* gstart  = (int*)(ws + 31066624);
    int* flagp   = (int*)(ws + 31068672);

    const size_t NEED = 31100000;
    if (ws_size < NEED) {
        unsigned int k = 0;
        while ((((size_t)1) << (k + 1)) <= ws_size && k < 62) k++;
        diag_kernel<<<1, 256, 0, stream>>>((unsigned short*)d_out,
                                           (unsigned short)(0x4000 | (k & 63)));
        return;
    }

    detect_kernel<<<1, 256, 0, stream>>>((const unsigned short*)d_in[0], flagp, bcnt);

    reorder_all_kernel<<<352, 256, 0, stream>>>(d_in[3], d_in[5], d_in[7], d_in[9],
                                                d_in[11], d_in[13], wfbase, flagp);

    // bucketed CSR build
    const int EB = (N_EDGES + 4095) / 4096;   // 196
    bcount_kernel<<<EB, 1024, 0, stream>>>(dstv, bcnt);
    bscan_kernel<<<1, 256, 0, stream>>>(bcnt, bbase, bcursor);
    bscatter_kernel<<<EB, 1024, 0, stream>>>(srcv, dstv, bcursor, ebuf);
    bsort_kernel<<<NBUCK, 256, 0, stream>>>(ebuf, bbase, off, csr);

    const int NBLK = (N_NODES + 255) / 256;   // 196
    gbounds_kernel<<<NBLK, 256, 0, stream>>>(batch, gstart, psum, pmax);

    cvt_x_kernel<<<12500, 256, 0, stream>>>(d_in[0], A, N_NODES * IN_DIM, flagp);

    const int GEMM_GRID = (N_NODES + 63) / 64;  // 782
    const int GATHER_GRID = (N_NODES + 3) / 4;  // 12500

    // layer 0: 64 -> 128 (A -> B -> A)
    gather_kernel<64><<<GATHER_GRID, 256, 0, stream>>>(A, off, csr, B);
    gin_mlp_kernel<64><<<GEMM_GRID, 256, 0, stream>>>(B, wfbase + 0 * 16384, d_in[4],
                                                      wfbase + 1 * 16384, d_in[6],
                                                      A, N_NODES, flagp);
    // layers 1,2: 128 -> 128 (A -> B -> A)
    for (int l = 1; l < 3; l++) {
        gather_kernel<128><<<GATHER_GRID, 256, 0, stream>>>(A, off, csr, B);
        gin_mlp_kernel<128><<<GEMM_GRID, 256, 0, stream>>>(B, wfbase + (2 * l) * 16384,
                                                           d_in[4 + 4 * l],
                                                           wfbase + (2 * l + 1) * 16384,
                                                           d_in[6 + 4 * l],
                                                           A, N_NODES, flagp);
    }

    // readout + head (h3 in A)
    dim3 pgrid(NUM_GRAPHS, POOL_SEG);
    pool_kernel<<<pgrid, 128, 0, stream>>>(A, gstart, psum, pmax);
    head_kernel<<<NUM_GRAPHS, 128, 0, stream>>>(psum, pmax, gstart,
                                                d_in[15], d_in[16], d_in[17], d_in[18],
                                                d_out, flagp);
}